// Round 9
// baseline (280.007 us; speedup 1.0000x reference)
//
#include <hip/hip_runtime.h>
#include <math.h>

#define NQ 20000
#define MS 20000
#define HN 32
#define CH 128
#define DH 64
#define KTOT 20
#define KMINI 7
#define EPSN 1e-5f
#define KDIM 2560            // KTOT*CH
#define NKT 80               // KDIM/32
#define NMT 1250             // NQ/16
#define KT_Y1 28             // kt < 28 -> y1 (k<7), else y2

// workspace layout (float units)
#define OFF_ROWSUM 0
#define OFF_Y1     20480
#define OFF_Y2     (OFF_Y1 + NQ*DH)
#define OFF_SEGSUM (OFF_Y2 + NQ*DH)           // 512, zeroed
#define OFF_BNSUM  (OFF_SEGSUM + 512)         // 128, zeroed
#define OFF_BNSQ   (OFF_BNSUM + 128)          // 128, zeroed
#define OFF_OUTPRE (OFF_BNSQ + 128)           // NQ*CH
#define OFF_WSWZ   (OFF_OUTPRE + NQ*CH)       // 327680 ushort
#define OFF_CFRAG  (OFF_WSWZ + 163840)        // 16384 ushort
#define OFF_XBF    (OFF_CFRAG + 8192)         // NQ*CH ushort
#define OFF_P      (OFF_XBF + NQ*CH/2)        // NQ*KDIM ushort (frag-ordered)
#define TOT_FLOATS (OFF_P + NQ*KDIM/2)

typedef __attribute__((ext_vector_type(8))) short bf16x8;
typedef __attribute__((ext_vector_type(4))) float f32x4;
typedef __attribute__((ext_vector_type(4))) unsigned short us4;
typedef __attribute__((ext_vector_type(8))) unsigned short us8;

static __device__ inline unsigned short f2bf(float f) {
    unsigned int u = __float_as_uint(f);
    unsigned int r = (u + 0x7fffu + ((u >> 16) & 1u)) >> 16;
    return (unsigned short)r;
}

// --- kernel P: rowsum+x_bf (<1250) | weight swizzle (<2530) | C frags (rest) --
__global__ __launch_bounds__(256) void k_prep(
    const float* __restrict__ x, float* __restrict__ rowsum,
    const float* __restrict__ w_mini, const float* __restrict__ w_mid,
    const float* __restrict__ w_midmini, const float* __restrict__ w_final,
    unsigned short* __restrict__ wswz, unsigned short* __restrict__ cfrag,
    unsigned short* __restrict__ x_bf)
{
    const int t = threadIdx.x;
    if (blockIdx.x < 1250) {
        int row = blockIdx.x * 16 + (t >> 4);
        int l16 = t & 15;
        const float4* xr = (const float4*)&x[(size_t)row * CH + l16 * 8];
        float4 a = xr[0], b = xr[1];
        if (x_bf) {
            us8 v;
            v[0] = f2bf(a.x); v[1] = f2bf(a.y); v[2] = f2bf(a.z); v[3] = f2bf(a.w);
            v[4] = f2bf(b.x); v[5] = f2bf(b.y); v[6] = f2bf(b.z); v[7] = f2bf(b.w);
            *(us8*)&x_bf[(size_t)row * CH + l16 * 8] = v;
        }
        double s = (double)a.x + a.y + a.z + a.w + b.x + b.y + b.z + b.w;
        #pragma unroll
        for (int off = 8; off > 0; off >>= 1) s += __shfl_down(s, off, 64);
        if (l16 == 0) rowsum[row] = (float)s;
    } else if (blockIdx.x < 2530) {
        int gid = (blockIdx.x - 1250) * 256 + t;
        if (gid >= NKT * 8 * 512) return;
        int j = gid & 7;
        int l = (gid >> 3) & 63;
        int ntkt = gid >> 9;
        int nt = ntkt & 7;
        int kt = ntkt >> 3;
        int kg = kt * 32 + ((l >> 4) << 3) + j;
        int d  = nt * 16 + (l & 15);
        int k = kg >> 7, c = kg & 127;
        float v = 0.0f;
        if (k < KMINI && d < DH)        v = w_mini[((size_t)k * CH + c) * DH + d];
        else if (k >= KMINI && d >= DH) v = w_mid[((size_t)(k - KMINI) * CH + c) * DH + (d - DH)];
        wswz[gid] = f2bf(v);
    } else {
        int b2 = blockIdx.x - 2530;            // 0..31 -> (kt, nt)
        int kt = b2 >> 3, nt = b2 & 7;
        for (int e = t; e < 512; e += 256) {
            int l = e >> 3, j = e & 7;
            int i = kt * 32 + ((l >> 4) << 3) + j;
            int jcol = nt * 16 + (l & 15);
            const float* wfr = &w_final[(size_t)jcol * 128 + 64];
            int ec = i & 63;
            float dsum = 0.f;
            #pragma unroll 8
            for (int dd = 0; dd < 64; ++dd)
                dsum += w_midmini[dd * 64 + ec] * wfr[dd];
            float cv = dsum + ((i < 64) ? w_final[(size_t)jcol * 128 + i] : 0.f);
            cfrag[(size_t)(kt * 8 + nt) * 512 + e] = f2bf(cv);
        }
    }
}

// ---------------- kernel W: MFMA weighting -> Pfrag ---------------------------
// 2500 blocks x 256 thr; block = 8 queries; wave w owns queries w*2, w*2+1.
// P_q[k][c] = sum_h wts[q][k][h] * x_bf[nidx[q][h]][c]   via 16x16x32 MFMA.
__global__ __launch_bounds__(256) void k_wgt(
    const float* __restrict__ q_pts, const float* __restrict__ s_pts,
    const int* __restrict__ inds, const unsigned short* __restrict__ x_bf,
    const float* __restrict__ kp_mini, const float* __restrict__ kp_mid,
    const float* __restrict__ rowsum,
    unsigned short* __restrict__ P)
{
    __shared__ __align__(16) unsigned short wts_t[8][32][40];   // A: [q][k(pad32)][h]
    __shared__ __align__(16) unsigned short XgT[4][128 * 40];   // B per wave: [c][h]
    __shared__ __align__(16) float nb[256][3];
    __shared__ int   nidx[256];
    __shared__ float kpts[KTOT][3];
    __shared__ int   vcnt[8];
    __shared__ float winv[8];

    const int t = threadIdx.x;
    const int l = t & 63;
    const int w = t >> 6;
    const int n0 = blockIdx.x * 8;
    const int c16 = l & 15;
    const int quad = l >> 4;

    if (t < KTOT * 3) {
        int k = t / 3, j = t % 3;
        kpts[k][j] = (k < KMINI) ? kp_mini[k * 3 + j] : kp_mid[(k - KMINI) * 3 + j];
    }
    if (t < 8) vcnt[t] = 0;
    __syncthreads();

    {   // 256 threads = 8 queries x 32 neighbors
        int r = t >> 5, h = t & 31;
        int n = n0 + r;
        int idx = inds[n * HN + h];
        nidx[t] = idx;
        float qx = q_pts[n * 3 + 0], qy = q_pts[n * 3 + 1], qz = q_pts[n * 3 + 2];
        nb[t][0] = s_pts[idx * 3 + 0] - qx;
        nb[t][1] = s_pts[idx * 3 + 1] - qy;
        nb[t][2] = s_pts[idx * 3 + 2] - qz;
        if (rowsum[idx] > 0.0f) atomicAdd(&vcnt[r], 1);
    }
    __syncthreads();
    if (t < 8) winv[t] = 1.0f / (float)max(vcnt[t], 1);
    __syncthreads();

    // build wts_t: 8 q x 32 k(pad) x 32 h = 8192 entries, bf16, zero for k>=20
    for (int tt = t; tt < 8 * 32 * 32; tt += 256) {
        int r = tt >> 10;
        int k = (tt >> 5) & 31;
        int h = tt & 31;
        float v = 0.f;
        if (k < KTOT) {
            float dx = nb[r * HN + h][0] - kpts[k][0];
            float dy = nb[r * HN + h][1] - kpts[k][1];
            float dz = nb[r * HN + h][2] - kpts[k][2];
            float sq = dx * dx + dy * dy + dz * dz;
            float dist = sqrtf(fmaxf(sq, 1e-12f));
            v = fmaxf(1.0f - dist * (1.0f / 0.6f), 0.0f) * winv[r];
        }
        wts_t[r][k][h] = f2bf(v);
    }
    __syncthreads();

    unsigned short* xt = &XgT[w][0];
    for (int step = 0; step < 2; ++step) {
        const int qi = w * 2 + step;
        const int n = n0 + qi;
        // gather + transpose into XgT[c][h] (wave-private; no barrier needed)
        #pragma unroll
        for (int i = 0; i < 8; ++i) {
            int id = i * 64 + l;
            int h = id & 31, cg = id >> 5;           // cg 0..15 (8 channels each)
            int idx = nidx[qi * HN + h];
            us8 v = *(const us8*)&x_bf[(size_t)idx * CH + cg * 8];
            #pragma unroll
            for (int e = 0; e < 8; ++e)
                xt[(cg * 8 + e) * 40 + h] = v[e];
        }
        // A fragments (k rows 0..15 and 16..31)
        bf16x8 a0 = *(const bf16x8*)&wts_t[qi][c16][quad * 8];
        bf16x8 a1 = *(const bf16x8*)&wts_t[qi][16 + c16][quad * 8];
        const int mt = n >> 4, n15 = n & 15;
        unsigned short* pbase = P + (size_t)mt * NKT * 512;
        #pragma unroll
        for (int nt = 0; nt < 8; ++nt) {
            bf16x8 b = *(const bf16x8*)&xt[(nt * 16 + c16) * 40 + quad * 8];
            f32x4 d0 = __builtin_amdgcn_mfma_f32_16x16x32_bf16(a0, b, (f32x4){0.f,0.f,0.f,0.f}, 0, 0, 0);
            f32x4 d1 = __builtin_amdgcn_mfma_f32_16x16x32_bf16(a1, b, (f32x4){0.f,0.f,0.f,0.f}, 0, 0, 0);
            const int c = nt * 16 + c16;
            const int lq = (c & 31) >> 3;            // consumer quad
            const int jj = c & 7;                    // consumer elem
            const int ktc = c >> 5;
            const size_t off = (size_t)lq * 16 * 8 + (size_t)n15 * 8 + jj;
            #pragma unroll
            for (int reg = 0; reg < 4; ++reg) {
                int k0 = quad * 4 + reg;             // 0..15
                pbase[(size_t)(k0 * 4 + ktc) * 512 + off] = f2bf(d0[reg]);
            }
            if (quad == 0) {
                #pragma unroll
                for (int reg = 0; reg < 4; ++reg) {
                    int k1 = 16 + reg;               // 16..19
                    pbase[(size_t)(k1 * 4 + ktc) * 512 + off] = f2bf(d1[reg]);
                }
            }
        }
    }
}

// ---------------- kernel M: frag-direct MFMA GEMM + fused segment stats -------
__global__ __launch_bounds__(256) void k_mfma(
    const unsigned short* __restrict__ P, const unsigned short* __restrict__ wswz,
    const int* __restrict__ stacklen,
    float* __restrict__ y1, float* __restrict__ y2, float* __restrict__ segsum)
{
    const int t = threadIdx.x;
    const int l = t & 63;
    const int w = t >> 6;
    const int chunk = blockIdx.y;
    const int mtb = blockIdx.x * 8 + w * 2;
    if (mtb >= NMT) return;
    const int kb = chunk ? KT_Y1 : 0;
    const int ke = chunk ? NKT : KT_Y1;
    const int ntb = chunk ? 4 : 0;

    f32x4 acc[2][4];
    #pragma unroll
    for (int i = 0; i < 2; ++i)
        #pragma unroll
        for (int q = 0; q < 4; ++q) acc[i][q] = (f32x4){0.f, 0.f, 0.f, 0.f};

    const size_t astride = (size_t)NKT * 512;
    const unsigned short* a0p = P + (size_t)mtb * astride + l * 8;
    const unsigned short* a1p = (mtb + 1 < NMT) ? a0p + astride : a0p;
    const unsigned short* bp = wswz + l * 8;

    #pragma unroll 2
    for (int kt = kb; kt < ke; ++kt) {
        bf16x8 a0 = *(const bf16x8*)(a0p + (size_t)kt * 512);
        bf16x8 a1 = *(const bf16x8*)(a1p + (size_t)kt * 512);
        #pragma unroll
        for (int q = 0; q < 4; ++q) {
            bf16x8 b = *(const bf16x8*)(bp + (size_t)((kt * 8) + ntb + q) * 512);
            acc[0][q] = __builtin_amdgcn_mfma_f32_16x16x32_bf16(a0, b, acc[0][q], 0, 0, 0);
            acc[1][q] = __builtin_amdgcn_mfma_f32_16x16x32_bf16(a1, b, acc[1][q], 0, 0, 0);
        }
    }

    const int len0 = stacklen[0];
    float* yb = chunk ? y2 : y1;
    const int quad = l >> 4, c16 = l & 15;
    const int base_sum = (chunk * 2) * 2 * 64;

    #pragma unroll
    for (int i = 0; i < 2; ++i) {
        int mt = mtb + i;
        if (mt >= NMT) break;
        bool all0 = (mt * 16 + 15 < len0);
        bool all1 = (mt * 16 >= len0);
        #pragma unroll
        for (int q = 0; q < 4; ++q) {
            float s0 = 0.f, q0 = 0.f, s1 = 0.f, q1 = 0.f;
            #pragma unroll
            for (int reg = 0; reg < 4; ++reg) {
                int row = mt * 16 + quad * 4 + reg;
                float v = acc[i][q][reg];
                yb[(size_t)row * DH + q * 16 + c16] = v;
                if (row < len0) { s0 += v; q0 += v * v; }
                else            { s1 += v; q1 += v * v; }
            }
            s0 += __shfl_xor(s0, 16); s0 += __shfl_xor(s0, 32);
            q0 += __shfl_xor(q0, 16); q0 += __shfl_xor(q0, 32);
            s1 += __shfl_xor(s1, 16); s1 += __shfl_xor(s1, 32);
            q1 += __shfl_xor(q1, 16); q1 += __shfl_xor(q1, 32);
            if (quad == 0) {
                int ch = q * 16 + c16;
                if (!all1) {
                    atomicAdd(&segsum[base_sum + 0 * 64 + ch], s0);
                    atomicAdd(&segsum[base_sum + 1 * 64 + ch], q0);
                }
                if (!all0) {
                    atomicAdd(&segsum[base_sum + 2 * 64 + ch], s1);
                    atomicAdd(&segsum[base_sum + 3 * 64 + ch], q1);
                }
            }
        }
    }
}

// -------- kernel T: fused tail GEMM (norm folded into A) + BN partials --------
__global__ __launch_bounds__(256) void k_tailmm(
    const float* __restrict__ y1, const float* __restrict__ y2,
    const float* __restrict__ segsum, const int* __restrict__ stacklen,
    const unsigned short* __restrict__ cfrag,
    float* __restrict__ outpre, float* __restrict__ bnsum, float* __restrict__ bnsq)
{
    __shared__ __align__(16) unsigned short alds[64 * 136];
    __shared__ float sstat[4][2][64];
    const int t = threadIdx.x;
    const int mb = blockIdx.x * 64;
    const int len0 = stacklen[0];

    {
        int combo = t >> 6, ch = t & 63;
        float cnt = (float)max((combo & 1) ? (NQ - len0) : len0, 1);
        float S = segsum[(combo * 2 + 0) * 64 + ch];
        float Q = segsum[(combo * 2 + 1) * 64 + ch];
        float mean = S / cnt;
        float var = Q / cnt - mean * mean;
        sstat[combo][0][ch] = mean;
        sstat[combo][1][ch] = rsqrtf(fmaxf(var, 0.f) + EPSN);
    }
    __syncthreads();

    for (int tt = t; tt < 64 * 32; tt += 256) {
        int r = tt >> 5, c4 = tt & 31;
        int n = mb + r;
        us4 v4 = (us4){0, 0, 0, 0};
        if (n < NQ) {
            int s = (n >= len0) ? 1 : 0;
            int c = c4 * 4;
            if (c < 64) {
                float4 yv = *(const float4*)&y1[(size_t)n * DH + c];
                v4[0] = f2bf((yv.x - sstat[s][0][c + 0]) * sstat[s][1][c + 0]);
                v4[1] = f2bf((yv.y - sstat[s][0][c + 1]) * sstat[s][1][c + 1]);
                v4[2] = f2bf((yv.z - sstat[s][0][c + 2]) * sstat[s][1][c + 2]);
                v4[3] = f2bf((yv.w - sstat[s][0][c + 3]) * sstat[s][1][c + 3]);
            } else {
                int c2 = c - 64;
                float4 yv = *(const float4*)&y2[(size_t)n * DH + c2];
                v4[0] = f2bf((yv.x - sstat[2 + s][0][c2 + 0]) * sstat[2 + s][1][c2 + 0]);
                v4[1] = f2bf((yv.y - sstat[2 + s][0][c2 + 1]) * sstat[2 + s][1][c2 + 1]);
                v4[2] = f2bf((yv.z - sstat[2 + s][0][c2 + 2]) * sstat[2 + s][1][c2 + 2]);
                v4[3] = f2bf((yv.w - sstat[2 + s][0][c2 + 3]) * sstat[2 + s][1][c2 + 3]);
            }
        }
        *(us4*)(alds + r * 136 + c4 * 4) = v4;
    }
    __syncthreads();

    const int l = t & 63, w = t >> 6;
    f32x4 acc[8];
    #pragma unroll
    for (int q = 0; q < 8; ++q) acc[q] = (f32x4){0.f, 0.f, 0.f, 0.f};

    const unsigned short* ap = alds + (w * 16 + (l & 15)) * 136 + ((l >> 4) << 3);
    const unsigned short* bp = cfrag + l * 8;
    #pragma unroll
    for (int kt = 0; kt < 4; ++kt) {
        bf16x8 a = *(const bf16x8*)(ap + kt * 32);
        #pragma unroll
        for (int nt = 0; nt < 8; ++nt) {
            bf16x8 b = *(const bf16x8*)(bp + (size_t)((kt * 8 + nt) << 9));
            acc[nt] = __builtin_amdgcn_mfma_f32_16x16x32_bf16(a, b, acc[nt], 0, 0, 0);
        }
    }

    const int quad = l >> 4, c16 = l & 15;
    #pragma unroll
    for (int nt = 0; nt < 8; ++nt) {
        float s = 0.f, q = 0.f;
        #pragma unroll
        for (int reg = 0; reg < 4; ++reg) {
            int row = mb + w * 16 + quad * 4 + reg;
            float v = acc[nt][reg];
            if (row < NQ) outpre[(size_t)row * CH + nt * 16 + c16] = v;
            else v = 0.f;
            s += v; q += v * v;
        }
        s += __shfl_xor(s, 16); s += __shfl_xor(s, 32);
        q += __shfl_xor(q, 16); q += __shfl_xor(q, 32);
        if (quad == 0) {
            atomicAdd(&bnsum[nt * 16 + c16], s);
            atomicAdd(&bnsq[nt * 16 + c16], q);
        }
    }
}

// ---------------- FALLBACK kernels (ws too small) -----------------------------
__global__ __launch_bounds__(256) void k_kpconv(
    const float* __restrict__ q_pts, const float* __restrict__ s_pts,
    const int* __restrict__ inds, const float* __restrict__ x,
    const float* __restrict__ kp_mini, const float* __restrict__ kp_mid,
    const float* __restrict__ w_mini, const float* __restrict__ w_mid,
    const float* __restrict__ rowsum,
    float* __restrict__ y1, float* __restrict__ y2)
{
    __shared__ __align__(16) float kpts[KTOT][3];
    __shared__ __align__(16) float nb[128][3];
    __shared__ int   nidx[128];
    __shared__ int   vcnt[4];
    __shared__ float winv[4];
    __shared__ __align__(16) float wts[4][HN][KTOT];
    __shared__ __align__(16) float wt[KTOT][CH][4];
    __shared__ __align__(16) float part[128][4];

    const int t = threadIdx.x;
    const int n0 = blockIdx.x * 4;

    if (t < KTOT * 3) {
        int k = t / 3, j = t % 3;
        kpts[k][j] = (k < KMINI) ? kp_mini[k * 3 + j] : kp_mid[(k - KMINI) * 3 + j];
    }
    if (t < 4) vcnt[t] = 0;
    __syncthreads();

    if (t < 128) {
        int r = t >> 5, h = t & 31;
        int n = n0 + r;
        int idx = inds[n * HN + h];
        nidx[t] = idx;
        float qx = q_pts[n * 3 + 0], qy = q_pts[n * 3 + 1], qz = q_pts[n * 3 + 2];
        nb[t][0] = s_pts[idx * 3 + 0] - qx;
        nb[t][1] = s_pts[idx * 3 + 1] - qy;
        nb[t][2] = s_pts[idx * 3 + 2] - qz;
        if (rowsum[idx] > 0.0f) atomicAdd(&vcnt[r], 1);
    }
    __syncthreads();
    if (t < 4) winv[t] = 1.0f / (float)max(vcnt[t], 1);
    __syncthreads();

    for (int tt = t; tt < 4 * HN * KTOT; tt += 256) {
        int r = tt / (HN * KTOT);
        int rem = tt % (HN * KTOT);
        int h = rem / KTOT, k = rem % KTOT;
        float dx = nb[r * HN + h][0] - kpts[k][0];
        float dy = nb[r * HN + h][1] - kpts[k][1];
        float dz = nb[r * HN + h][2] - kpts[k][2];
        float sq = dx * dx + dy * dy + dz * dz;
        float dist = sqrtf(fmaxf(sq, 1e-12f));
        float w = fmaxf(1.0f - dist * (1.0f / 0.6f), 0.0f);
        wts[r][h][k] = w * winv[r];
    }
    __syncthreads();

    {
        const int g = t >> 7;
        const int c = t & 127;
        for (int rr = 0; rr < 2; ++rr) {
            const int r = g + rr * 2;
            float acc[KTOT];
            #pragma unroll
            for (int k = 0; k < KTOT; ++k) acc[k] = 0.0f;
            for (int h = 0; h < HN; ++h) {
                int idx = nidx[r * HN + h];
                float xv = x[(size_t)idx * CH + c];
                const float4* wp = (const float4*)&wts[r][h][0];
                float4 wa = wp[0], wb = wp[1], wc = wp[2], wd = wp[3], we = wp[4];
                acc[0]  += wa.x * xv; acc[1]  += wa.y * xv; acc[2]  += wa.z * xv; acc[3]  += wa.w * xv;
                acc[4]  += wb.x * xv; acc[5]  += wb.y * xv; acc[6]  += wb.z * xv; acc[7]  += wb.w * xv;
                acc[8]  += wc.x * xv; acc[9]  += wc.y * xv; acc[10] += wc.z * xv; acc[11] += wc.w * xv;
                acc[12] += wd.x * xv; acc[13] += wd.y * xv; acc[14] += wd.z * xv; acc[15] += wd.w * xv;
                acc[16] += we.x * xv; acc[17] += we.y * xv; acc[18] += we.z * xv; acc[19] += we.w * xv;
            }
            #pragma unroll
            for (int k = 0; k < KTOT; ++k) wt[k][c][r] = acc[k];
        }
    }
    __syncthreads();

    {
        const int d = t & 127;
        const int half = t >> 7;
        const int c0 = half * 64;
        float o0 = 0.f, o1 = 0.f, o2 = 0.f, o3 = 0.f;
        if (d < DH) {
            for (int k = 0; k < KMINI; ++k) {
                const float* wp = &w_mini[((size_t)k * CH + c0) * DH + d];
                for (int c = c0; c < c0 + 64; ++c) {
                    float wv = *wp; wp += DH;
                    const float4 wtv = *(const float4*)&wt[k][c][0];
                    o0 += wv * wtv.x; o1 += wv * wtv.y; o2 += wv * wtv.z; o3 += wv * wtv.w;
                }
            }
        } else {
            const int dd = d - DH;
            for (int k = KMINI; k < KTOT; ++k) {
                const float* wp = &w_mid[((size_t)(k - KMINI) * CH + c0) * DH + dd];
                for (int c = c0; c < c0 + 64; ++c) {
                    float wv = *wp; wp += DH;
                    const float4 wtv = *(const float4*)&wt[k][c][0];
                    o0 += wv * wtv.x; o1 += wv * wtv.y; o2 += wv * wtv.z; o3 += wv * wtv.w;
                }
            }
        }
        if (half == 1) { part[d][0] = o0; part[d][1] = o1; part[d][2] = o2; part[d][3] = o3; }
        __syncthreads();
        if (half == 0) {
            o0 += part[d][0]; o1 += part[d][1]; o2 += part[d][2]; o3 += part[d][3];
            if (d < DH) {
                y1[(size_t)(n0 + 0) * DH + d] = o0;
                y1[(size_t)(n0 + 1) * DH + d] = o1;
                y1[(size_t)(n0 + 2) * DH + d] = o2;
                y1[(size_t)(n0 + 3) * DH + d] = o3;
            } else {
                const int dd = d - DH;
                y2[(size_t)(n0 + 0) * DH + dd] = o0;
                y2[(size_t)(n0 + 1) * DH + dd] = o1;
                y2[(size_t)(n0 + 2) * DH + dd] = o2;
                y2[(size_t)(n0 + 3) * DH + dd] = o3;
            }
        }
    }
}

__global__ __launch_bounds__(256) void k_segpart(
    const float* __restrict__ y1, const float* __restrict__ y2,
    const int* __restrict__ stacklen, float* __restrict__ segsum)
{
    const int t = threadIdx.x;
    const int ch = t & 63, grp = t >> 6;
    const int len0 = stacklen[0];
    float a0 = 0.f, a1 = 0.f, a2 = 0.f, a3 = 0.f;
    float b0 = 0.f, b1 = 0.f, b2 = 0.f, b3 = 0.f;
    for (int r = blockIdx.x * 4 + grp; r < NQ; r += 256 * 4) {
        float v1 = y1[(size_t)r * DH + ch];
        float v2 = y2[(size_t)r * DH + ch];
        bool in1 = (r >= len0);
        float m0 = in1 ? 0.f : 1.f, m1 = 1.f - m0;
        a0 += m0 * v1; a1 += m0 * v1 * v1; a2 += m1 * v1; a3 += m1 * v1 * v1;
        b0 += m0 * v2; b1 += m0 * v2 * v2; b2 += m1 * v2; b3 += m1 * v2 * v2;
    }
    __shared__ float red[4][8][64];
    red[grp][0][ch] = a0; red[grp][1][ch] = a1; red[grp][2][ch] = a2; red[grp][3][ch] = a3;
    red[grp][4][ch] = b0; red[grp][5][ch] = b1; red[grp][6][ch] = b2; red[grp][7][ch] = b3;
    __syncthreads();
    for (int tt = t; tt < 512; tt += 256) {
        int j = tt >> 6, c = tt & 63;
        float s = red[0][j][c] + red[1][j][c] + red[2][j][c] + red[3][j][c];
        atomicAdd(&segsum[j * 64 + c], s);
    }
}

__global__ __launch_bounds__(256) void k_tail(
    const float* __restrict__ y1, const float* __restrict__ y2,
    const float* __restrict__ segsum, const int* __restrict__ stacklen,
    const float* __restrict__ w_midmini, const float* __restrict__ w_final,
    float* __restrict__ outpre, float* __restrict__ bnsum, float* __restrict__ bnsq)
{
    __shared__ __align__(16) float sstat[4][2][64];
    __shared__ __align__(16) float sbuf[8][64];
    __shared__ __align__(16) float xc[8][128];
    __shared__ float lsum[2][128], lsq[2][128];
    const int n0 = blockIdx.x * 8;
    const int t = threadIdx.x;
    const int len0 = stacklen[0];

    {
        int combo = t >> 6, ch = t & 63;
        float cnt = (float)max((combo & 1) ? (NQ - len0) : len0, 1);
        float S = segsum[(combo * 2 + 0) * 64 + ch];
        float Q = segsum[(combo * 2 + 1) * 64 + ch];
        float mean = S / cnt;
        float var = Q / cnt - mean * mean;
        sstat[combo][0][ch] = mean;
        sstat[combo][1][ch] = rsqrtf(fmaxf(var, 0.f) + EPSN);
    }
    __syncthreads();

    for (int tt = t; tt < 8 * 64; tt += 256) {
        int r = tt >> 6, d = tt & 63;
        int n = n0 + r;
        int s = (n >= len0) ? 1 : 0;
        float x1n = (y1[(size_t)n * DH + d] - sstat[s][0][d]) * sstat[s][1][d];
        float x2n = (y2[(size_t)n * DH + d] - sstat[2 + s][0][d]) * sstat[2 + s][1][d];
        xc[r][d] = x1n;
        sbuf[r][d] = x1n + x2n;
    }
    __syncthreads();

    for (int tt = t; tt < 8 * 64; tt += 256) {
        int r = tt >> 6, d = tt & 63;
        float a = 0.f;
        const float4* wmr = (const float4*)&w_midmini[(size_t)d * 64];
        const float4* sv = (const float4*)&sbuf[r][0];
        #pragma unroll
        for (int e4 = 0; e4 < 16; ++e4) {
            float4 w4 = wmr[e4], s4 = sv[e4];
            a += w4.x * s4.x + w4.y * s4.y + w4.z * s4.z + w4.w * s4.w;
        }
        xc[r][64 + d] = a;
    }
    __syncthreads();

    {
        const int j = t & 127;
        const int g = t >> 7;
        float o0 = 0.f, o1 = 0.f, o2 = 0.f, o3 = 0.f;
        const float4* wfr = (const float4*)&w_final[(size_t)j * 128];
        #pragma unroll 8
        for (int i4 = 0; i4 < 32; ++i4) {
            float4 wf = wfr[i4];
            float4 a0 = *(const float4*)&xc[g + 0][i4 * 4];
            float4 a1 = *(const float4*)&xc[g + 2][i4 * 4];
            float4 a2 = *(const float4*)&xc[g + 4][i4 * 4];
            float4 a3 = *(const float4*)&xc[g + 6][i4 * 4];
            o0 += wf.x * a0.x + wf.y * a0.y + wf.z * a0.z + wf.w * a0.w;
            o1 += wf.x * a1.x + wf.y * a1.y + wf.z * a1.z + wf.w * a1.w;
            o2 += wf.x * a2.x + wf.y * a2.y + wf.z * a2.z + wf.w * a2.w;
            o3 += wf.x * a3.x + wf.y * a3.y + wf.z * a3.z + wf.w * a3.w;
        }
        outpre[(size_t)(n0 + g + 0) * CH + j] = o0;
        outpre[(size_t)(n0 + g + 2) * CH + j] = o1;
        outpre[(size_t)(n0 + g + 4) * CH + j] = o2;
        outpre[(size_t)(n0 + g + 6) * CH + j] = o3;
        lsum[g][j] = o0 + o1 + o2 + o3;
        lsq[g][j]  = o0 * o0 + o1 * o1 + o2 * o2 + o3 * o3;
        __syncthreads();
        if (g == 0) {
            atomicAdd(&bnsum[j], lsum[0][j] + lsum[1][j]);
            atomicAdd(&bnsq[j],  lsq[0][j] + lsq[1][j]);
        }
    }
}

// ---------------- kernel 5: BN apply + relu ----------------------------------
__global__ __launch_bounds__(256) void k_bnapply(const float* __restrict__ outpre,
    const float* __restrict__ bnsum, const float* __restrict__ bnsq,
    const float* __restrict__ gamma, const float* __restrict__ beta,
    float* __restrict__ out)
{
    int e4 = blockIdx.x * 256 + threadIdx.x;
    if (e4 >= NQ * CH / 4) return;
    int j0 = (e4 * 4) & 127;
    float4 v = ((const float4*)outpre)[e4];
    float vv[4] = {v.x, v.y, v.z, v.w};
    float res[4];
    #pragma unroll
    for (int i = 0; i < 4; ++i) {
        int j = j0 + i;
        float mean = bnsum[j] * (1.0f / NQ);
        float var = bnsq[j] * (1.0f / NQ) - mean * mean;
        float rstd = rsqrtf(fmaxf(var, 0.f) + EPSN);
        float r = (vv[i] - mean) * rstd * gamma[j] + beta[j];
        res[i] = fmaxf(r, 0.f);
    }
    ((float4*)out)[e4] = make_float4(res[0], res[1], res[2], res[3]);
}

extern "C" void kernel_launch(void* const* d_in, const int* in_sizes, int n_in,
                              void* d_out, int out_size, void* d_ws, size_t ws_size,
                              hipStream_t stream) {
    const float* q_pts     = (const float*)d_in[0];
    const float* s_pts     = (const float*)d_in[1];
    const int*   inds      = (const int*)d_in[2];
    const float* x         = (const float*)d_in[3];
    const int*   stacklen  = (const int*)d_in[4];
    const float* kp_mini   = (const float*)d_in[5];
    const float* w_mini    = (const float*)d_in[6];
    const float* kp_mid    = (const float*)d_in[7];
    const float* w_mid     = (const float*)d_in[8];
    const float* w_midmini = (const float*)d_in[9];
    const float* w_final   = (const float*)d_in[10];
    const float* gamma     = (const float*)d_in[11];
    const float* beta      = (const float*)d_in[12];

    float* ws      = (float*)d_ws;
    float* rowsum  = ws + OFF_ROWSUM;
    float* y1      = ws + OFF_Y1;
    float* y2      = ws + OFF_Y2;
    float* segsum  = ws + OFF_SEGSUM;
    float* bnsum   = ws + OFF_BNSUM;
    float* bnsq    = ws + OFF_BNSQ;
    float* outpre  = ws + OFF_OUTPRE;
    unsigned short* wswz  = (unsigned short*)(ws + OFF_WSWZ);
    unsigned short* cfrag = (unsigned short*)(ws + OFF_CFRAG);
    unsigned short* x_bf  = (unsigned short*)(ws + OFF_XBF);
    unsigned short* P     = (unsigned short*)(ws + OFF_P);

    hipMemsetAsync(segsum, 0, 768 * sizeof(float), stream);

    if (ws_size >= (size_t)TOT_FLOATS * sizeof(float)) {
        k_prep<<<1250 + 1280 + 32, 256, 0, stream>>>(x, rowsum, w_mini, w_mid,
                                                     w_midmini, w_final, wswz, cfrag, x_bf);
        k_wgt<<<NQ / 8, 256, 0, stream>>>(q_pts, s_pts, inds, x_bf, kp_mini, kp_mid,
                                          rowsum, P);
        dim3 mg((NMT + 7) / 8, 2);
        k_mfma<<<mg, 256, 0, stream>>>(P, wswz, stacklen, y1, y2, segsum);
        k_tailmm<<<(NQ + 63) / 64, 256, 0, stream>>>(y1, y2, segsum, stacklen, cfrag,
                                                     outpre, bnsum, bnsq);
    } else {
        k_prep<<<1250, 256, 0, stream>>>(x, rowsum, w_mini, w_mid,
                                         w_midmini, w_final, wswz, cfrag, (unsigned short*)0);
        k_kpconv<<<NQ / 4, 256, 0, stream>>>(q_pts, s_pts, inds, x, kp_mini, kp_mid,
                                             w_mini, w_mid, rowsum, y1, y2);
        k_segpart<<<256, 256, 0, stream>>>(y1, y2, stacklen, segsum);
        k_tail<<<NQ / 8, 256, 0, stream>>>(y1, y2, segsum, stacklen, w_midmini, w_final,
                                           outpre, bnsum, bnsq);
    }

    k_bnapply<<<(NQ * CH / 4 + 255) / 256, 256, 0, stream>>>(outpre, bnsum, bnsq,
                                                             gamma, beta, (float*)d_out);
}

// Round 10
// 261.032 us; speedup vs baseline: 1.0727x; 1.0727x over previous
//
#include <hip/hip_runtime.h>
#include <math.h>

#define NQ 20000
#define MS 20000
#define HN 32
#define CH 128
#define DH 64
#define KTOT 20
#define KMINI 7
#define EPSN 1e-5f
#define KDIM 2560            // KTOT*CH
#define NKT 80               // KDIM/32
#define NMT 1250             // NQ/16
#define KT_Y1 28             // kt < 28 -> y1 (k<7), else y2

// workspace layout (float units)
#define OFF_ROWSUM 0
#define OFF_Y1     20480
#define OFF_Y2     (OFF_Y1 + NQ*DH)
#define OFF_SEGSUM (OFF_Y2 + NQ*DH)           // 512, zeroed
#define OFF_BNSUM  (OFF_SEGSUM + 512)         // 128, zeroed
#define OFF_BNSQ   (OFF_BNSUM + 128)          // 128, zeroed
#define OFF_OUTPRE (OFF_BNSQ + 128)           // NQ*CH
#define OFF_WSWZ   (OFF_OUTPRE + NQ*CH)       // 327680 ushort
#define OFF_CFRAG  (OFF_WSWZ + 163840)        // 16384 ushort
#define OFF_P      (OFF_CFRAG + 8192)         // NQ*KDIM ushort (frag-ordered)
#define TOT_FLOATS (OFF_P + NQ*KDIM/2)

typedef __attribute__((ext_vector_type(8))) short bf16x8;
typedef __attribute__((ext_vector_type(4))) float f32x4;
typedef __attribute__((ext_vector_type(4))) unsigned short us4;

static __device__ inline unsigned short f2bf(float f) {
    unsigned int u = __float_as_uint(f);
    unsigned int r = (u + 0x7fffu + ((u >> 16) & 1u)) >> 16;
    return (unsigned short)r;
}

// --- kernel P: rowsum (<5000) | weight swizzle (<6280) | fused-C frags (rest) -
__global__ __launch_bounds__(256) void k_prep(
    const float* __restrict__ x, float* __restrict__ rowsum,
    const float* __restrict__ w_mini, const float* __restrict__ w_mid,
    const float* __restrict__ w_midmini, const float* __restrict__ w_final,
    unsigned short* __restrict__ wswz, unsigned short* __restrict__ cfrag)
{
    if (blockIdx.x < 5000) {
        int row = blockIdx.x * 4 + (threadIdx.x >> 6);
        int lane = threadIdx.x & 63;
        if (row >= MS) return;
        double s = (double)x[row * CH + lane] + (double)x[row * CH + 64 + lane];
        #pragma unroll
        for (int off = 32; off > 0; off >>= 1) s += __shfl_down(s, off, 64);
        if (lane == 0) rowsum[row] = (float)s;
    } else if (blockIdx.x < 6280) {
        int gid = (blockIdx.x - 5000) * 256 + threadIdx.x;
        if (gid >= NKT * 8 * 512) return;
        int j = gid & 7;
        int l = (gid >> 3) & 63;
        int ntkt = gid >> 9;
        int nt = ntkt & 7;
        int kt = ntkt >> 3;
        int kg = kt * 32 + ((l >> 4) << 3) + j;
        int d  = nt * 16 + (l & 15);
        int k = kg >> 7, c = kg & 127;
        float v = 0.0f;
        if (k < KMINI && d < DH)        v = w_mini[((size_t)k * CH + c) * DH + d];
        else if (k >= KMINI && d >= DH) v = w_mid[((size_t)(k - KMINI) * CH + c) * DH + (d - DH)];
        wswz[gid] = f2bf(v);
    } else {
        int b2 = blockIdx.x - 6280;            // 0..31 -> (kt, nt)
        int kt = b2 >> 3, nt = b2 & 7;
        for (int e = threadIdx.x; e < 512; e += 256) {
            int l = e >> 3, j = e & 7;
            int i = kt * 32 + ((l >> 4) << 3) + j;
            int jcol = nt * 16 + (l & 15);
            const float* wfr = &w_final[(size_t)jcol * 128 + 64];
            int ec = i & 63;
            float dsum = 0.f;
            #pragma unroll 8
            for (int dd = 0; dd < 64; ++dd)
                dsum += w_midmini[dd * 64 + ec] * wfr[dd];
            float cv = dsum + ((i < 64) ? w_final[(size_t)jcol * 128 + i] : 0.f);
            cfrag[(size_t)(kt * 8 + nt) * 512 + e] = f2bf(cv);
        }
    }
}

// ---------------- kernel G: gather + influence -> Pfrag (MFMA A-frag order) ---
__global__ __launch_bounds__(256) void k_gather(
    const float* __restrict__ q_pts, const float* __restrict__ s_pts,
    const int* __restrict__ inds, const float* __restrict__ x,
    const float* __restrict__ kp_mini, const float* __restrict__ kp_mid,
    const float* __restrict__ rowsum,
    unsigned short* __restrict__ P)
{
    __shared__ __align__(16) float kpts[KTOT][3];
    __shared__ __align__(16) float nb[256][3];
    __shared__ int   nidx[256];
    __shared__ int   vcnt[8];
    __shared__ float winv[8];
    __shared__ __align__(16) float wts[8][HN][KTOT];

    const int t = threadIdx.x;
    const int n0 = blockIdx.x * 8;

    if (t < KTOT * 3) {
        int k = t / 3, j = t % 3;
        kpts[k][j] = (k < KMINI) ? kp_mini[k * 3 + j] : kp_mid[(k - KMINI) * 3 + j];
    }
    if (t < 8) vcnt[t] = 0;
    __syncthreads();

    {   // 256 threads = 8 rows x 32 neighbors
        int r = t >> 5, h = t & 31;
        int n = n0 + r;
        int idx = inds[n * HN + h];
        nidx[t] = idx;
        float qx = q_pts[n * 3 + 0], qy = q_pts[n * 3 + 1], qz = q_pts[n * 3 + 2];
        nb[t][0] = s_pts[idx * 3 + 0] - qx;
        nb[t][1] = s_pts[idx * 3 + 1] - qy;
        nb[t][2] = s_pts[idx * 3 + 2] - qz;
        if (rowsum[idx] > 0.0f) atomicAdd(&vcnt[r], 1);
    }
    __syncthreads();
    if (t < 8) winv[t] = 1.0f / (float)max(vcnt[t], 1);
    __syncthreads();

    for (int tt = t; tt < 8 * HN * KTOT; tt += 256) {
        int r = tt / (HN * KTOT);
        int rem = tt % (HN * KTOT);
        int h = rem / KTOT, k = rem % KTOT;
        float dx = nb[r * HN + h][0] - kpts[k][0];
        float dy = nb[r * HN + h][1] - kpts[k][1];
        float dz = nb[r * HN + h][2] - kpts[k][2];
        float sq = dx * dx + dy * dy + dz * dz;
        float dist = sqrtf(fmaxf(sq, 1e-12f));
        float w = fmaxf(1.0f - dist * (1.0f / 0.6f), 0.0f);
        wts[r][h][k] = w * winv[r];
    }
    __syncthreads();

    const int r = t >> 5;
    const int c4 = t & 31;
    float acc[KTOT][4];
    #pragma unroll
    for (int k = 0; k < KTOT; ++k) {
        acc[k][0] = 0.f; acc[k][1] = 0.f; acc[k][2] = 0.f; acc[k][3] = 0.f;
    }
    const float* wbase = &wts[r][0][0];
    const int* nid = &nidx[r * HN];
    #pragma unroll 2
    for (int h = 0; h < HN; ++h) {
        int idx = nid[h];
        float4 xv = *(const float4*)&x[(size_t)idx * CH + c4 * 4];
        const float4* wp = (const float4*)(wbase + h * KTOT);
        float warr[20];
        *(float4*)&warr[0]  = wp[0];
        *(float4*)&warr[4]  = wp[1];
        *(float4*)&warr[8]  = wp[2];
        *(float4*)&warr[12] = wp[3];
        *(float4*)&warr[16] = wp[4];
        #pragma unroll
        for (int k = 0; k < KTOT; ++k) {
            float wv = warr[k];
            acc[k][0] += wv * xv.x; acc[k][1] += wv * xv.y;
            acc[k][2] += wv * xv.z; acc[k][3] += wv * xv.w;
        }
    }
    const int n = n0 + r;
    const int mt = n >> 4, m15 = n & 15;
    const int lq = (c4 & 7) >> 1;
    const int l = lq * 16 + m15;
    const int j = (c4 & 1) * 4;
    #pragma unroll
    for (int k = 0; k < KTOT; ++k) {
        int kt = k * 4 + (c4 >> 3);
        us4 v;
        v[0] = f2bf(acc[k][0]); v[1] = f2bf(acc[k][1]);
        v[2] = f2bf(acc[k][2]); v[3] = f2bf(acc[k][3]);
        *(us4*)(P + ((size_t)mt * NKT + kt) * 512 + l * 8 + j) = v;
    }
}

// ---------------- kernel M: frag-direct MFMA GEMM + fused segment stats -------
// grid (313, 2); wave = 1 M-tile (4 tiles/block) for 2x grid occupancy.
__global__ __launch_bounds__(256) void k_mfma(
    const unsigned short* __restrict__ P, const unsigned short* __restrict__ wswz,
    const int* __restrict__ stacklen,
    float* __restrict__ y1, float* __restrict__ y2, float* __restrict__ segsum)
{
    const int t = threadIdx.x;
    const int l = t & 63;
    const int w = t >> 6;
    const int chunk = blockIdx.y;
    const int mt = blockIdx.x * 4 + w;
    if (mt >= NMT) return;
    const int kb = chunk ? KT_Y1 : 0;
    const int ke = chunk ? NKT : KT_Y1;
    const int ntb = chunk ? 4 : 0;

    f32x4 acc[4];
    #pragma unroll
    for (int q = 0; q < 4; ++q) acc[q] = (f32x4){0.f, 0.f, 0.f, 0.f};

    const unsigned short* ap = P + (size_t)mt * NKT * 512 + l * 8;
    const unsigned short* bp = wswz + l * 8;

    #pragma unroll 2
    for (int kt = kb; kt < ke; ++kt) {
        bf16x8 a = *(const bf16x8*)(ap + (size_t)kt * 512);
        #pragma unroll
        for (int q = 0; q < 4; ++q) {
            bf16x8 b = *(const bf16x8*)(bp + (size_t)((kt * 8) + ntb + q) * 512);
            acc[q] = __builtin_amdgcn_mfma_f32_16x16x32_bf16(a, b, acc[q], 0, 0, 0);
        }
    }

    const int len0 = stacklen[0];
    float* yb = chunk ? y2 : y1;
    const int quad = l >> 4, c16 = l & 15;
    const int base_sum = (chunk * 2) * 2 * 64;

    bool all0 = (mt * 16 + 15 < len0);
    bool all1 = (mt * 16 >= len0);
    #pragma unroll
    for (int q = 0; q < 4; ++q) {
        float s0 = 0.f, q0 = 0.f, s1 = 0.f, q1 = 0.f;
        #pragma unroll
        for (int reg = 0; reg < 4; ++reg) {
            int row = mt * 16 + quad * 4 + reg;
            float v = acc[q][reg];
            yb[(size_t)row * DH + q * 16 + c16] = v;
            if (row < len0) { s0 += v; q0 += v * v; }
            else            { s1 += v; q1 += v * v; }
        }
        s0 += __shfl_xor(s0, 16); s0 += __shfl_xor(s0, 32);
        q0 += __shfl_xor(q0, 16); q0 += __shfl_xor(q0, 32);
        s1 += __shfl_xor(s1, 16); s1 += __shfl_xor(s1, 32);
        q1 += __shfl_xor(q1, 16); q1 += __shfl_xor(q1, 32);
        if (quad == 0) {
            int ch = q * 16 + c16;
            if (!all1) {
                atomicAdd(&segsum[base_sum + 0 * 64 + ch], s0);
                atomicAdd(&segsum[base_sum + 1 * 64 + ch], q0);
            }
            if (!all0) {
                atomicAdd(&segsum[base_sum + 2 * 64 + ch], s1);
                atomicAdd(&segsum[base_sum + 3 * 64 + ch], q1);
            }
        }
    }
}

// -------- kernel T: fused tail GEMM (norm folded into A) + BN partials --------
// 128-thread blocks over 32-row tiles -> grid 625 (2.4 blocks/CU).
__global__ __launch_bounds__(128) void k_tailmm(
    const float* __restrict__ y1, const float* __restrict__ y2,
    const float* __restrict__ segsum, const int* __restrict__ stacklen,
    const unsigned short* __restrict__ cfrag,
    float* __restrict__ outpre, float* __restrict__ bnsum, float* __restrict__ bnsq)
{
    __shared__ __align__(16) unsigned short alds[32 * 136];
    __shared__ float sstat[4][2][64];
    const int t = threadIdx.x;
    const int mb = blockIdx.x * 32;
    const int len0 = stacklen[0];

    for (int tt = t; tt < 256; tt += 128) {
        int combo = tt >> 6, ch = tt & 63;
        float cnt = (float)max((combo & 1) ? (NQ - len0) : len0, 1);
        float S = segsum[(combo * 2 + 0) * 64 + ch];
        float Q = segsum[(combo * 2 + 1) * 64 + ch];
        float mean = S / cnt;
        float var = Q / cnt - mean * mean;
        sstat[combo][0][ch] = mean;
        sstat[combo][1][ch] = rsqrtf(fmaxf(var, 0.f) + EPSN);
    }
    __syncthreads();

    for (int tt = t; tt < 32 * 32; tt += 128) {
        int r = tt >> 5, c4 = tt & 31;
        int n = mb + r;
        us4 v4 = (us4){0, 0, 0, 0};
        if (n < NQ) {
            int s = (n >= len0) ? 1 : 0;
            int c = c4 * 4;
            if (c < 64) {
                float4 yv = *(const float4*)&y1[(size_t)n * DH + c];
                v4[0] = f2bf((yv.x - sstat[s][0][c + 0]) * sstat[s][1][c + 0]);
                v4[1] = f2bf((yv.y - sstat[s][0][c + 1]) * sstat[s][1][c + 1]);
                v4[2] = f2bf((yv.z - sstat[s][0][c + 2]) * sstat[s][1][c + 2]);
                v4[3] = f2bf((yv.w - sstat[s][0][c + 3]) * sstat[s][1][c + 3]);
            } else {
                int c2 = c - 64;
                float4 yv = *(const float4*)&y2[(size_t)n * DH + c2];
                v4[0] = f2bf((yv.x - sstat[2 + s][0][c2 + 0]) * sstat[2 + s][1][c2 + 0]);
                v4[1] = f2bf((yv.y - sstat[2 + s][0][c2 + 1]) * sstat[2 + s][1][c2 + 1]);
                v4[2] = f2bf((yv.z - sstat[2 + s][0][c2 + 2]) * sstat[2 + s][1][c2 + 2]);
                v4[3] = f2bf((yv.w - sstat[2 + s][0][c2 + 3]) * sstat[2 + s][1][c2 + 3]);
            }
        }
        *(us4*)(alds + r * 136 + c4 * 4) = v4;
    }
    __syncthreads();

    const int l = t & 63, w = t >> 6;
    f32x4 acc[8];
    #pragma unroll
    for (int q = 0; q < 8; ++q) acc[q] = (f32x4){0.f, 0.f, 0.f, 0.f};

    const unsigned short* ap = alds + (w * 16 + (l & 15)) * 136 + ((l >> 4) << 3);
    const unsigned short* bp = cfrag + l * 8;
    #pragma unroll
    for (int kt = 0; kt < 4; ++kt) {
        bf16x8 a = *(const bf16x8*)(ap + kt * 32);
        #pragma unroll
        for (int nt = 0; nt < 8; ++nt) {
            bf16x8 b = *(const bf16x8*)(bp + (size_t)((kt * 8 + nt) << 9));
            acc[nt] = __builtin_amdgcn_mfma_f32_16x16x32_bf16(a, b, acc[nt], 0, 0, 0);
        }
    }

    const int quad = l >> 4, c16 = l & 15;
    #pragma unroll
    for (int nt = 0; nt < 8; ++nt) {
        float s = 0.f, q = 0.f;
        #pragma unroll
        for (int reg = 0; reg < 4; ++reg) {
            int row = mb + w * 16 + quad * 4 + reg;
            float v = acc[nt][reg];
            if (row < NQ) outpre[(size_t)row * CH + nt * 16 + c16] = v;
            else v = 0.f;
            s += v; q += v * v;
        }
        s += __shfl_xor(s, 16); s += __shfl_xor(s, 32);
        q += __shfl_xor(q, 16); q += __shfl_xor(q, 32);
        if (quad == 0) {
            atomicAdd(&bnsum[nt * 16 + c16], s);
            atomicAdd(&bnsq[nt * 16 + c16], q);
        }
    }
}

// ---------------- FALLBACK kernels (ws too small) -----------------------------
__global__ __launch_bounds__(256) void k_kpconv(
    const float* __restrict__ q_pts, const float* __restrict__ s_pts,
    const int* __restrict__ inds, const float* __restrict__ x,
    const float* __restrict__ kp_mini, const float* __restrict__ kp_mid,
    const float* __restrict__ w_mini, const float* __restrict__ w_mid,
    const float* __restrict__ rowsum,
    float* __restrict__ y1, float* __restrict__ y2)
{
    __shared__ __align__(16) float kpts[KTOT][3];
    __shared__ __align__(16) float nb[128][3];
    __shared__ int   nidx[128];
    __shared__ int   vcnt[4];
    __shared__ float winv[4];
    __shared__ __align__(16) float wts[4][HN][KTOT];
    __shared__ __align__(16) float wt[KTOT][CH][4];
    __shared__ __align__(16) float part[128][4];

    const int t = threadIdx.x;
    const int n0 = blockIdx.x * 4;

    if (t < KTOT * 3) {
        int k = t / 3, j = t % 3;
        kpts[k][j] = (k < KMINI) ? kp_mini[k * 3 + j] : kp_mid[(k - KMINI) * 3 + j];
    }
    if (t < 4) vcnt[t] = 0;
    __syncthreads();

    if (t < 128) {
        int r = t >> 5, h = t & 31;
        int n = n0 + r;
        int idx = inds[n * HN + h];
        nidx[t] = idx;
        float qx = q_pts[n * 3 + 0], qy = q_pts[n * 3 + 1], qz = q_pts[n * 3 + 2];
        nb[t][0] = s_pts[idx * 3 + 0] - qx;
        nb[t][1] = s_pts[idx * 3 + 1] - qy;
        nb[t][2] = s_pts[idx * 3 + 2] - qz;
        if (rowsum[idx] > 0.0f) atomicAdd(&vcnt[r], 1);
    }
    __syncthreads();
    if (t < 4) winv[t] = 1.0f / (float)max(vcnt[t], 1);
    __syncthreads();

    for (int tt = t; tt < 4 * HN * KTOT; tt += 256) {
        int r = tt / (HN * KTOT);
        int rem = tt % (HN * KTOT);
        int h = rem / KTOT, k = rem % KTOT;
        float dx = nb[r * HN + h][0] - kpts[k][0];
        float dy = nb[r * HN + h][1] - kpts[k][1];
        float dz = nb[r * HN + h][2] - kpts[k][2];
        float sq = dx * dx + dy * dy + dz * dz;
        float dist = sqrtf(fmaxf(sq, 1e-12f));
        float w = fmaxf(1.0f - dist * (1.0f / 0.6f), 0.0f);
        wts[r][h][k] = w * winv[r];
    }
    __syncthreads();

    {
        const int g = t >> 7;
        const int c = t & 127;
        for (int rr = 0; rr < 2; ++rr) {
            const int r = g + rr * 2;
            float acc[KTOT];
            #pragma unroll
            for (int k = 0; k < KTOT; ++k) acc[k] = 0.0f;
            for (int h = 0; h < HN; ++h) {
                int idx = nidx[r * HN + h];
                float xv = x[(size_t)idx * CH + c];
                const float4* wp = (const float4*)&wts[r][h][0];
                float4 wa = wp[0], wb = wp[1], wc = wp[2], wd = wp[3], we = wp[4];
                acc[0]  += wa.x * xv; acc[1]  += wa.y * xv; acc[2]  += wa.z * xv; acc[3]  += wa.w * xv;
                acc[4]  += wb.x * xv; acc[5]  += wb.y * xv; acc[6]  += wb.z * xv; acc[7]  += wb.w * xv;
                acc[8]  += wc.x * xv; acc[9]  += wc.y * xv; acc[10] += wc.z * xv; acc[11] += wc.w * xv;
                acc[12] += wd.x * xv; acc[13] += wd.y * xv; acc[14] += wd.z * xv; acc[15] += wd.w * xv;
                acc[16] += we.x * xv; acc[17] += we.y * xv; acc[18] += we.z * xv; acc[19] += we.w * xv;
            }
            #pragma unroll
            for (int k = 0; k < KTOT; ++k) wt[k][c][r] = acc[k];
        }
    }
    __syncthreads();

    {
        const int d = t & 127;
        const int half = t >> 7;
        const int c0 = half * 64;
        float o0 = 0.f, o1 = 0.f, o2 = 0.f, o3 = 0.f;
        if (d < DH) {
            for (int k = 0; k < KMINI; ++k) {
                const float* wp = &w_mini[((size_t)k * CH + c0) * DH + d];
                for (int c = c0; c < c0 + 64; ++c) {
                    float wv = *wp; wp += DH;
                    const float4 wtv = *(const float4*)&wt[k][c][0];
                    o0 += wv * wtv.x; o1 += wv * wtv.y; o2 += wv * wtv.z; o3 += wv * wtv.w;
                }
            }
        } else {
            const int dd = d - DH;
            for (int k = KMINI; k < KTOT; ++k) {
                const float* wp = &w_mid[((size_t)(k - KMINI) * CH + c0) * DH + dd];
                for (int c = c0; c < c0 + 64; ++c) {
                    float wv = *wp; wp += DH;
                    const float4 wtv = *(const float4*)&wt[k][c][0];
                    o0 += wv * wtv.x; o1 += wv * wtv.y; o2 += wv * wtv.z; o3 += wv * wtv.w;
                }
            }
        }
        if (half == 1) { part[d][0] = o0; part[d][1] = o1; part[d][2] = o2; part[d][3] = o3; }
        __syncthreads();
        if (half == 0) {
            o0 += part[d][0]; o1 += part[d][1]; o2 += part[d][2]; o3 += part[d][3];
            if (d < DH) {
                y1[(size_t)(n0 + 0) * DH + d] = o0;
                y1[(size_t)(n0 + 1) * DH + d] = o1;
                y1[(size_t)(n0 + 2) * DH + d] = o2;
                y1[(size_t)(n0 + 3) * DH + d] = o3;
            } else {
                const int dd = d - DH;
                y2[(size_t)(n0 + 0) * DH + dd] = o0;
                y2[(size_t)(n0 + 1) * DH + dd] = o1;
                y2[(size_t)(n0 + 2) * DH + dd] = o2;
                y2[(size_t)(n0 + 3) * DH + dd] = o3;
            }
        }
    }
}

__global__ __launch_bounds__(256) void k_segpart(
    const float* __restrict__ y1, const float* __restrict__ y2,
    const int* __restrict__ stacklen, float* __restrict__ segsum)
{
    const int t = threadIdx.x;
    const int ch = t & 63, grp = t >> 6;
    const int len0 = stacklen[0];
    float a0 = 0.f, a1 = 0.f, a2 = 0.f, a3 = 0.f;
    float b0 = 0.f, b1 = 0.f, b2 = 0.f, b3 = 0.f;
    for (int r = blockIdx.x * 4 + grp; r < NQ; r += 256 * 4) {
        float v1 = y1[(size_t)r * DH + ch];
        float v2 = y2[(size_t)r * DH + ch];
        bool in1 = (r >= len0);
        float m0 = in1 ? 0.f : 1.f, m1 = 1.f - m0;
        a0 += m0 * v1; a1 += m0 * v1 * v1; a2 += m1 * v1; a3 += m1 * v1 * v1;
        b0 += m0 * v2; b1 += m0 * v2 * v2; b2 += m1 * v2; b3 += m1 * v2 * v2;
    }
    __shared__ float red[4][8][64];
    red[grp][0][ch] = a0; red[grp][1][ch] = a1; red[grp][2][ch] = a2; red[grp][3][ch] = a3;
    red[grp][4][ch] = b0; red[grp][5][ch] = b1; red[grp][6][ch] = b2; red[grp][7][ch] = b3;
    __syncthreads();
    for (int tt = t; tt < 512; tt += 256) {
        int j = tt >> 6, c = tt & 63;
        float s = red[0][j][c] + red[1][j][c] + red[2][j][c] + red[3][j][c];
        atomicAdd(&segsum[j * 64 + c], s);
    }
}

__global__ __launch_bounds__(256) void k_tail(
    const float* __restrict__ y1, const float* __restrict__ y2,
    const float* __restrict__ segsum, const int* __restrict__ stacklen,
    const float* __restrict__ w_midmini, const float* __restrict__ w_final,
    float* __restrict__ outpre, float* __restrict__ bnsum, float* __restrict__ bnsq)
{
    __shared__ __align__(16) float sstat[4][2][64];
    __shared__ __align__(16) float sbuf[8][64];
    __shared__ __align__(16) float xc[8][128];
    __shared__ float lsum[2][128], lsq[2][128];
    const int n0 = blockIdx.x * 8;
    const int t = threadIdx.x;
    const int len0 = stacklen[0];

    {
        int combo = t >> 6, ch = t & 63;
        float cnt = (float)max((combo & 1) ? (NQ - len0) : len0, 1);
        float S = segsum[(combo * 2 + 0) * 64 + ch];
        float Q = segsum[(combo * 2 + 1) * 64 + ch];
        float mean = S / cnt;
        float var = Q / cnt - mean * mean;
        sstat[combo][0][ch] = mean;
        sstat[combo][1][ch] = rsqrtf(fmaxf(var, 0.f) + EPSN);
    }
    __syncthreads();

    for (int tt = t; tt < 8 * 64; tt += 256) {
        int r = tt >> 6, d = tt & 63;
        int n = n0 + r;
        int s = (n >= len0) ? 1 : 0;
        float x1n = (y1[(size_t)n * DH + d] - sstat[s][0][d]) * sstat[s][1][d];
        float x2n = (y2[(size_t)n * DH + d] - sstat[2 + s][0][d]) * sstat[2 + s][1][d];
        xc[r][d] = x1n;
        sbuf[r][d] = x1n + x2n;
    }
    __syncthreads();

    for (int tt = t; tt < 8 * 64; tt += 256) {
        int r = tt >> 6, d = tt & 63;
        float a = 0.f;
        const float4* wmr = (const float4*)&w_midmini[(size_t)d * 64];
        const float4* sv = (const float4*)&sbuf[r][0];
        #pragma unroll
        for (int e4 = 0; e4 < 16; ++e4) {
            float4 w4 = wmr[e4], s4 = sv[e4];
            a += w4.x * s4.x + w4.y * s4.y + w4.z * s4.z + w4.w * s4.w;
        }
        xc[r][64 + d] = a;
    }
    __syncthreads();

    {
        const int j = t & 127;
        const int g = t >> 7;
        float o0 = 0.f, o1 = 0.f, o2 = 0.f, o3 = 0.f;
        const float4* wfr = (const float4*)&w_final[(size_t)j * 128];
        #pragma unroll 8
        for (int i4 = 0; i4 < 32; ++i4) {
            float4 wf = wfr[i4];
            float4 a0 = *(const float4*)&xc[g + 0][i4 * 4];
            float4 a1 = *(const float4*)&xc[g + 2][i4 * 4];
            float4 a2 = *(const float4*)&xc[g + 4][i4 * 4];
            float4 a3 = *(const float4*)&xc[g + 6][i4 * 4];
            o0 += wf.x * a0.x + wf.y * a0.y + wf.z * a0.z + wf.w * a0.w;
            o1 += wf.x * a1.x + wf.y * a1.y + wf.z * a1.z + wf.w * a1.w;
            o2 += wf.x * a2.x + wf.y * a2.y + wf.z * a2.z + wf.w * a2.w;
            o3 += wf.x * a3.x + wf.y * a3.y + wf.z * a3.z + wf.w * a3.w;
        }
        outpre[(size_t)(n0 + g + 0) * CH + j] = o0;
        outpre[(size_t)(n0 + g + 2) * CH + j] = o1;
        outpre[(size_t)(n0 + g + 4) * CH + j] = o2;
        outpre[(size_t)(n0 + g + 6) * CH + j] = o3;
        lsum[g][j] = o0 + o1 + o2 + o3;
        lsq[g][j]  = o0 * o0 + o1 * o1 + o2 * o2 + o3 * o3;
        __syncthreads();
        if (g == 0) {
            atomicAdd(&bnsum[j], lsum[0][j] + lsum[1][j]);
            atomicAdd(&bnsq[j],  lsq[0][j] + lsq[1][j]);
        }
    }
}

// ---------------- kernel 5: BN apply + relu ----------------------------------
__global__ __launch_bounds__(256) void k_bnapply(const float* __restrict__ outpre,
    const float* __restrict__ bnsum, const float* __restrict__ bnsq,
    const float* __restrict__ gamma, const float* __restrict__ beta,
    float* __restrict__ out)
{
    int e4 = blockIdx.x * 256 + threadIdx.x;
    if (e4 >= NQ * CH / 4) return;
    int j0 = (e4 * 4) & 127;
    float4 v = ((const float4*)outpre)[e4];
    float vv[4] = {v.x, v.y, v.z, v.w};
    float res[4];
    #pragma unroll
    for (int i = 0; i < 4; ++i) {
        int j = j0 + i;
        float mean = bnsum[j] * (1.0f / NQ);
        float var = bnsq[j] * (1.0f / NQ) - mean * mean;
        float rstd = rsqrtf(fmaxf(var, 0.f) + EPSN);
        float r = (vv[i] - mean) * rstd * gamma[j] + beta[j];
        res[i] = fmaxf(r, 0.f);
    }
    ((float4*)out)[e4] = make_float4(res[0], res[1], res[2], res[3]);
}

extern "C" void kernel_launch(void* const* d_in, const int* in_sizes, int n_in,
                              void* d_out, int out_size, void* d_ws, size_t ws_size,
                              hipStream_t stream) {
    const float* q_pts     = (const float*)d_in[0];
    const float* s_pts     = (const float*)d_in[1];
    const int*   inds      = (const int*)d_in[2];
    const float* x         = (const float*)d_in[3];
    const int*   stacklen  = (const int*)d_in[4];
    const float* kp_mini   = (const float*)d_in[5];
    const float* w_mini    = (const float*)d_in[6];
    const float* kp_mid    = (const float*)d_in[7];
    const float* w_mid     = (const float*)d_in[8];
    const float* w_midmini = (const float*)d_in[9];
    const float* w_final   = (const float*)d_in[10];
    const float* gamma     = (const float*)d_in[11];
    const float* beta      = (const float*)d_in[12];

    float* ws      = (float*)d_ws;
    float* rowsum  = ws + OFF_ROWSUM;
    float* y1      = ws + OFF_Y1;
    float* y2      = ws + OFF_Y2;
    float* segsum  = ws + OFF_SEGSUM;
    float* bnsum   = ws + OFF_BNSUM;
    float* bnsq    = ws + OFF_BNSQ;
    float* outpre  = ws + OFF_OUTPRE;
    unsigned short* wswz  = (unsigned short*)(ws + OFF_WSWZ);
    unsigned short* cfrag = (unsigned short*)(ws + OFF_CFRAG);
    unsigned short* P     = (unsigned short*)(ws + OFF_P);

    hipMemsetAsync(segsum, 0, 768 * sizeof(float), stream);

    if (ws_size >= (size_t)TOT_FLOATS * sizeof(float)) {
        k_prep<<<5000 + 1280 + 32, 256, 0, stream>>>(x, rowsum, w_mini, w_mid,
                                                     w_midmini, w_final, wswz, cfrag);
        k_gather<<<NQ / 8, 256, 0, stream>>>(q_pts, s_pts, inds, x, kp_mini, kp_mid,
                                             rowsum, P);
        dim3 mg((NMT + 3) / 4, 2);
        k_mfma<<<mg, 256, 0, stream>>>(P, wswz, stacklen, y1, y2, segsum);
        k_tailmm<<<(NQ + 31) / 32, 128, 0, stream>>>(y1, y2, segsum, stacklen, cfrag,
                                                     outpre, bnsum, bnsq);
    } else {
        k_prep<<<5000, 256, 0, stream>>>(x, rowsum, w_mini, w_mid,
                                         w_midmini, w_final, wswz, cfrag);
        k_kpconv<<<NQ / 4, 256, 0, stream>>>(q_pts, s_pts, inds, x, kp_mini, kp_mid,
                                             w_mini, w_mid, rowsum, y1, y2);
        k_segpart<<<256, 256, 0, stream>>>(y1, y2, stacklen, segsum);
        k_tail<<<NQ / 8, 256, 0, stream>>>(y1, y2, segsum, stacklen, w_midmini, w_final,
                                           outpre, bnsum, bnsq);
    }

    k_bnapply<<<(NQ * CH / 4 + 255) / 256, 256, 0, stream>>>(outpre, bnsum, bnsq,
                                                             gamma, beta, (float*)d_out);
}

// Round 11
// 232.603 us; speedup vs baseline: 1.2038x; 1.1222x over previous
//
#include <hip/hip_runtime.h>
#include <math.h>

#define NQ 20000
#define MS 20000
#define HN 32
#define CH 128
#define DH 64
#define KTOT 20
#define KMINI 7
#define EPSN 1e-5f
#define NKT 80
#define KT_Y1 28

// workspace layout (float units)
#define OFF_ROWSUM 0
#define OFF_Y1     20480
#define OFF_Y2     (OFF_Y1 + NQ*DH)
#define OFF_SEGSUM (OFF_Y2 + NQ*DH)           // 512, zeroed
#define OFF_BNSUM  (OFF_SEGSUM + 512)         // 128, zeroed
#define OFF_BNSQ   (OFF_BNSUM + 128)          // 128, zeroed
#define OFF_OUTPRE (OFF_BNSQ + 128)           // NQ*CH
#define OFF_WSWZ   (OFF_OUTPRE + NQ*CH)       // 327680 ushort
#define OFF_CFRAG  (OFF_WSWZ + 163840)        // 16384 ushort
#define TOT_FLOATS (OFF_CFRAG + 8192)

// Pt LDS pitches (elements): 16-byte aligned, bank-spread
#define PK 40                 // k-row stride
#define PQ 840                // query stride (21*40)

typedef __attribute__((ext_vector_type(8))) short bf16x8;
typedef __attribute__((ext_vector_type(4))) float f32x4;
typedef __attribute__((ext_vector_type(4))) unsigned short us4;

static __device__ inline unsigned short f2bf(float f) {
    unsigned int u = __float_as_uint(f);
    unsigned int r = (u + 0x7fffu + ((u >> 16) & 1u)) >> 16;
    return (unsigned short)r;
}

// --- kernel P: rowsum (<5000) | weight swizzle (<6280) | fused-C frags (rest) -
__global__ __launch_bounds__(256) void k_prep(
    const float* __restrict__ x, float* __restrict__ rowsum,
    const float* __restrict__ w_mini, const float* __restrict__ w_mid,
    const float* __restrict__ w_midmini, const float* __restrict__ w_final,
    unsigned short* __restrict__ wswz, unsigned short* __restrict__ cfrag)
{
    if (blockIdx.x < 5000) {
        int row = blockIdx.x * 4 + (threadIdx.x >> 6);
        int lane = threadIdx.x & 63;
        if (row >= MS) return;
        double s = (double)x[row * CH + lane] + (double)x[row * CH + 64 + lane];
        #pragma unroll
        for (int off = 32; off > 0; off >>= 1) s += __shfl_down(s, off, 64);
        if (lane == 0) rowsum[row] = (float)s;
    } else if (blockIdx.x < 6280) {
        int gid = (blockIdx.x - 5000) * 256 + threadIdx.x;
        if (gid >= NKT * 8 * 512) return;
        int j = gid & 7;
        int l = (gid >> 3) & 63;
        int ntkt = gid >> 9;
        int nt = ntkt & 7;
        int kt = ntkt >> 3;
        int kg = kt * 32 + ((l >> 4) << 3) + j;
        int d  = nt * 16 + (l & 15);
        int k = kg >> 7, c = kg & 127;
        float v = 0.0f;
        if (k < KMINI && d < DH)        v = w_mini[((size_t)k * CH + c) * DH + d];
        else if (k >= KMINI && d >= DH) v = w_mid[((size_t)(k - KMINI) * CH + c) * DH + (d - DH)];
        wswz[gid] = f2bf(v);
    } else {
        int b2 = blockIdx.x - 6280;
        int kt = b2 >> 3, nt = b2 & 7;
        for (int e = threadIdx.x; e < 512; e += 256) {
            int l = e >> 3, j = e & 7;
            int i = kt * 32 + ((l >> 4) << 3) + j;
            int jcol = nt * 16 + (l & 15);
            const float* wfr = &w_final[(size_t)jcol * 128 + 64];
            int ec = i & 63;
            float dsum = 0.f;
            #pragma unroll 8
            for (int dd = 0; dd < 64; ++dd)
                dsum += w_midmini[dd * 64 + ec] * wfr[dd];
            float cv = dsum + ((i < 64) ? w_final[(size_t)jcol * 128 + i] : 0.f);
            cfrag[(size_t)(kt * 8 + nt) * 512 + e] = f2bf(cv);
        }
    }
}

// --------- kernel F2: fused gather + MFMA weighting + MFMA main GEMM ----------
// 1250 blocks x 256 thr; block = 16 queries. P lives only in LDS (c-quartered).
__global__ __launch_bounds__(256) void k_fused2(
    const float* __restrict__ q_pts, const float* __restrict__ s_pts,
    const int* __restrict__ inds, const float* __restrict__ x,
    const float* __restrict__ kp_mini, const float* __restrict__ kp_mid,
    const float* __restrict__ rowsum, const unsigned short* __restrict__ wswz,
    const int* __restrict__ stacklen,
    float* __restrict__ y1, float* __restrict__ y2, float* __restrict__ segsum)
{
    // pool: Pt [16][PQ=840] ushort (26880 B) | xg [4 waves][32 h][36 c] ushort (9216 B)
    // nbv [16][32][3] float (6144 B) aliases Pt region during phases 0-1.
    __shared__ __align__(16) char pool[36096];
    unsigned short* Pt = (unsigned short*)pool;
    unsigned short* xg = (unsigned short*)(pool + 26880);
    float* nbv = (float*)pool;
    __shared__ int nidx[512];
    __shared__ float kpts[KTOT][3];
    __shared__ int vcnt[16];
    __shared__ float winv[16];

    const int t = threadIdx.x;
    const int l = t & 63;
    const int w = t >> 6;
    const int c16 = l & 15;
    const int quad = l >> 4;
    const int n0 = blockIdx.x * 16;

    if (t < KTOT * 3) {
        int k = t / 3, j = t % 3;
        kpts[k][j] = (k < KMINI) ? kp_mini[k * 3 + j] : kp_mid[(k - KMINI) * 3 + j];
    }
    if (t < 16) vcnt[t] = 0;
    __syncthreads();

    // phase 0: neighbor vectors + validity counts
    for (int tt = t; tt < 512; tt += 256) {
        int r = tt >> 5, h = tt & 31;
        int n = n0 + r;
        int idx = inds[n * HN + h];
        nidx[tt] = idx;
        float qx = q_pts[n * 3 + 0], qy = q_pts[n * 3 + 1], qz = q_pts[n * 3 + 2];
        nbv[tt * 3 + 0] = s_pts[idx * 3 + 0] - qx;
        nbv[tt * 3 + 1] = s_pts[idx * 3 + 1] - qy;
        nbv[tt * 3 + 2] = s_pts[idx * 3 + 2] - qz;
        if (rowsum[idx] > 0.0f) atomicAdd(&vcnt[r], 1);
    }
    __syncthreads();
    if (t < 16) winv[t] = 1.0f / (float)max(vcnt[t], 1);
    __syncthreads();

    // phase 1: influence A-fragments in registers (k rows 0..15 and 16..19)
    bf16x8 aw0[4], aw1[4];
    const float k0x = kpts[c16][0], k0y = kpts[c16][1], k0z = kpts[c16][2];
    const bool v1 = (c16 < 4);
    const float k1x = v1 ? kpts[16 + c16][0] : 0.f;
    const float k1y = v1 ? kpts[16 + c16][1] : 0.f;
    const float k1z = v1 ? kpts[16 + c16][2] : 0.f;
    #pragma unroll
    for (int s = 0; s < 4; ++s) {
        const int qi = w * 4 + s;
        const float wi = winv[qi];
        const float* nvb = nbv + (qi * 32 + quad * 8) * 3;
        #pragma unroll
        for (int j = 0; j < 8; ++j) {
            float bx = nvb[j * 3 + 0], by = nvb[j * 3 + 1], bz = nvb[j * 3 + 2];
            float dx = bx - k0x, dy = by - k0y, dz = bz - k0z;
            float d = sqrtf(fmaxf(dx * dx + dy * dy + dz * dz, 1e-12f));
            aw0[s][j] = (short)f2bf(fmaxf(1.0f - d * (1.0f / 0.6f), 0.0f) * wi);
            if (v1) {
                dx = bx - k1x; dy = by - k1y; dz = bz - k1z;
                d = sqrtf(fmaxf(dx * dx + dy * dy + dz * dz, 1e-12f));
                aw1[s][j] = (short)f2bf(fmaxf(1.0f - d * (1.0f / 0.6f), 0.0f) * wi);
            } else {
                aw1[s][j] = 0;
            }
        }
    }
    __syncthreads();   // nbv dead; Pt/xg region live

    f32x4 accY1 = (f32x4){0.f, 0.f, 0.f, 0.f};
    f32x4 accY2 = (f32x4){0.f, 0.f, 0.f, 0.f};
    unsigned short* xgw = xg + w * (32 * 36);
    const f32x4 zero4 = (f32x4){0.f, 0.f, 0.f, 0.f};

    for (int ktc = 0; ktc < 4; ++ktc) {
        // weighting: each wave produces Pt rows for its 4 queries, this c-quarter
        #pragma unroll
        for (int s = 0; s < 4; ++s) {
            const int qi = w * 4 + s;
            #pragma unroll
            for (int i = 0; i < 4; ++i) {
                int gid = i * 64 + l;
                int h = gid >> 3, c4i = gid & 7;
                int idx = nidx[qi * 32 + h];
                float4 xv = *(const float4*)&x[(size_t)idx * CH + ktc * 32 + c4i * 4];
                us4 v;
                v[0] = f2bf(xv.x); v[1] = f2bf(xv.y); v[2] = f2bf(xv.z); v[3] = f2bf(xv.w);
                *(us4*)&xgw[h * 36 + c4i * 4] = v;
            }
            asm volatile("s_waitcnt lgkmcnt(0)" ::: "memory");
            #pragma unroll
            for (int cf = 0; cf < 2; ++cf) {
                bf16x8 bb;
                #pragma unroll
                for (int j = 0; j < 8; ++j)
                    bb[j] = (short)xgw[(quad * 8 + j) * 36 + cf * 16 + c16];
                f32x4 d0 = __builtin_amdgcn_mfma_f32_16x16x32_bf16(aw0[s], bb, zero4, 0, 0, 0);
                f32x4 d1 = __builtin_amdgcn_mfma_f32_16x16x32_bf16(aw1[s], bb, zero4, 0, 0, 0);
                unsigned short* pq = Pt + qi * PQ + cf * 16 + c16;
                #pragma unroll
                for (int reg = 0; reg < 4; ++reg)
                    pq[(quad * 4 + reg) * PK] = f2bf(d0[reg]);
                if (quad == 0) {
                    #pragma unroll
                    for (int reg = 0; reg < 4; ++reg)
                        pq[(16 + reg) * PK] = f2bf(d1[reg]);
                }
            }
        }
        __syncthreads();   // Pt complete for this c-quarter

        // main GEMM: wave w owns output col-tiles nt=w (y1) and 4+w (y2)
        #pragma unroll
        for (int k = 0; k < KTOT; ++k) {
            int ktg = k * 4 + ktc;
            bf16x8 a = *(const bf16x8*)&Pt[c16 * PQ + k * PK + quad * 8];
            int nt = (k < KMINI) ? w : 4 + w;
            bf16x8 b = *(const bf16x8*)&wswz[((size_t)(ktg * 8 + nt) << 9) + l * 8];
            if (k < KMINI) accY1 = __builtin_amdgcn_mfma_f32_16x16x32_bf16(a, b, accY1, 0, 0, 0);
            else           accY2 = __builtin_amdgcn_mfma_f32_16x16x32_bf16(a, b, accY2, 0, 0, 0);
        }
        __syncthreads();   // before next pass overwrites Pt/xg
    }

    // epilogue: store y + fused segment stats. rows m = quad*4+reg, col = w*16+c16
    const int len0 = stacklen[0];
    const bool all0 = (n0 + 15 < len0);
    const bool all1 = (n0 >= len0);
    const int ch = w * 16 + c16;
    #pragma unroll
    for (int half = 0; half < 2; ++half) {
        f32x4 acc = half ? accY2 : accY1;
        float* yb = half ? y2 : y1;
        const int sbase = half ? 256 : 0;
        float s0 = 0.f, q0 = 0.f, s1 = 0.f, q1 = 0.f;
        #pragma unroll
        for (int reg = 0; reg < 4; ++reg) {
            int row = n0 + quad * 4 + reg;
            float v = acc[reg];
            yb[(size_t)row * DH + ch] = v;
            if (row < len0) { s0 += v; q0 += v * v; }
            else            { s1 += v; q1 += v * v; }
        }
        s0 += __shfl_xor(s0, 16); s0 += __shfl_xor(s0, 32);
        q0 += __shfl_xor(q0, 16); q0 += __shfl_xor(q0, 32);
        s1 += __shfl_xor(s1, 16); s1 += __shfl_xor(s1, 32);
        q1 += __shfl_xor(q1, 16); q1 += __shfl_xor(q1, 32);
        if (quad == 0) {
            if (!all1) {
                atomicAdd(&segsum[sbase + 0 * 64 + ch], s0);
                atomicAdd(&segsum[sbase + 1 * 64 + ch], q0);
            }
            if (!all0) {
                atomicAdd(&segsum[sbase + 2 * 64 + ch], s1);
                atomicAdd(&segsum[sbase + 3 * 64 + ch], q1);
            }
        }
    }
}

// -------- kernel T: fused tail GEMM (norm folded into A) + BN partials --------
__global__ __launch_bounds__(128) void k_tailmm(
    const float* __restrict__ y1, const float* __restrict__ y2,
    const float* __restrict__ segsum, const int* __restrict__ stacklen,
    const unsigned short* __restrict__ cfrag,
    float* __restrict__ outpre, float* __restrict__ bnsum, float* __restrict__ bnsq)
{
    __shared__ __align__(16) unsigned short alds[32 * 136];
    __shared__ float sstat[4][2][64];
    const int t = threadIdx.x;
    const int mb = blockIdx.x * 32;
    const int len0 = stacklen[0];

    for (int tt = t; tt < 256; tt += 128) {
        int combo = tt >> 6, ch = tt & 63;
        float cnt = (float)max((combo & 1) ? (NQ - len0) : len0, 1);
        float S = segsum[(combo * 2 + 0) * 64 + ch];
        float Q = segsum[(combo * 2 + 1) * 64 + ch];
        float mean = S / cnt;
        float var = Q / cnt - mean * mean;
        sstat[combo][0][ch] = mean;
        sstat[combo][1][ch] = rsqrtf(fmaxf(var, 0.f) + EPSN);
    }
    __syncthreads();

    for (int tt = t; tt < 32 * 32; tt += 128) {
        int r = tt >> 5, c4 = tt & 31;
        int n = mb + r;
        us4 v4 = (us4){0, 0, 0, 0};
        if (n < NQ) {
            int s = (n >= len0) ? 1 : 0;
            int c = c4 * 4;
            if (c < 64) {
                float4 yv = *(const float4*)&y1[(size_t)n * DH + c];
                v4[0] = f2bf((yv.x - sstat[s][0][c + 0]) * sstat[s][1][c + 0]);
                v4[1] = f2bf((yv.y - sstat[s][0][c + 1]) * sstat[s][1][c + 1]);
                v4[2] = f2bf((yv.z - sstat[s][0][c + 2]) * sstat[s][1][c + 2]);
                v4[3] = f2bf((yv.w - sstat[s][0][c + 3]) * sstat[s][1][c + 3]);
            } else {
                int c2 = c - 64;
                float4 yv = *(const float4*)&y2[(size_t)n * DH + c2];
                v4[0] = f2bf((yv.x - sstat[2 + s][0][c2 + 0]) * sstat[2 + s][1][c2 + 0]);
                v4[1] = f2bf((yv.y - sstat[2 + s][0][c2 + 1]) * sstat[2 + s][1][c2 + 1]);
                v4[2] = f2bf((yv.z - sstat[2 + s][0][c2 + 2]) * sstat[2 + s][1][c2 + 2]);
                v4[3] = f2bf((yv.w - sstat[2 + s][0][c2 + 3]) * sstat[2 + s][1][c2 + 3]);
            }
        }
        *(us4*)(alds + r * 136 + c4 * 4) = v4;
    }
    __syncthreads();

    const int l = t & 63, w = t >> 6;
    f32x4 acc[8];
    #pragma unroll
    for (int q = 0; q < 8; ++q) acc[q] = (f32x4){0.f, 0.f, 0.f, 0.f};

    const unsigned short* ap = alds + (w * 16 + (l & 15)) * 136 + ((l >> 4) << 3);
    const unsigned short* bp = cfrag + l * 8;
    #pragma unroll
    for (int kt = 0; kt < 4; ++kt) {
        bf16x8 a = *(const bf16x8*)(ap + kt * 32);
        #pragma unroll
        for (int nt = 0; nt < 8; ++nt) {
            bf16x8 b = *(const bf16x8*)(bp + (size_t)((kt * 8 + nt) << 9));
            acc[nt] = __builtin_amdgcn_mfma_f32_16x16x32_bf16(a, b, acc[nt], 0, 0, 0);
        }
    }

    const int quad = l >> 4, c16 = l & 15;
    #pragma unroll
    for (int nt = 0; nt < 8; ++nt) {
        float s = 0.f, q = 0.f;
        #pragma unroll
        for (int reg = 0; reg < 4; ++reg) {
            int row = mb + w * 16 + quad * 4 + reg;
            float v = acc[nt][reg];
            if (row < NQ) outpre[(size_t)row * CH + nt * 16 + c16] = v;
            else v = 0.f;
            s += v; q += v * v;
        }
        s += __shfl_xor(s, 16); s += __shfl_xor(s, 32);
        q += __shfl_xor(q, 16); q += __shfl_xor(q, 32);
        if (quad == 0) {
            atomicAdd(&bnsum[nt * 16 + c16], s);
            atomicAdd(&bnsq[nt * 16 + c16], q);
        }
    }
}

// ---------------- FALLBACK kernels (ws too small) -----------------------------
__global__ __launch_bounds__(256) void k_kpconv(
    const float* __restrict__ q_pts, const float* __restrict__ s_pts,
    const int* __restrict__ inds, const float* __restrict__ x,
    const float* __restrict__ kp_mini, const float* __restrict__ kp_mid,
    const float* __restrict__ w_mini, const float* __restrict__ w_mid,
    const float* __restrict__ rowsum,
    float* __restrict__ y1, float* __restrict__ y2)
{
    __shared__ __align__(16) float kpts[KTOT][3];
    __shared__ __align__(16) float nb[128][3];
    __shared__ int   nidx[128];
    __shared__ int   vcnt[4];
    __shared__ float winv[4];
    __shared__ __align__(16) float wts[4][HN][KTOT];
    __shared__ __align__(16) float wt[KTOT][CH][4];
    __shared__ __align__(16) float part[128][4];

    const int t = threadIdx.x;
    const int n0 = blockIdx.x * 4;

    if (t < KTOT * 3) {
        int k = t / 3, j = t % 3;
        kpts[k][j] = (k < KMINI) ? kp_mini[k * 3 + j] : kp_mid[(k - KMINI) * 3 + j];
    }
    if (t < 4) vcnt[t] = 0;
    __syncthreads();

    if (t < 128) {
        int r = t >> 5, h = t & 31;
        int n = n0 + r;
        int idx = inds[n * HN + h];
        nidx[t] = idx;
        float qx = q_pts[n * 3 + 0], qy = q_pts[n * 3 + 1], qz = q_pts[n * 3 + 2];
        nb[t][0] = s_pts[idx * 3 + 0] - qx;
        nb[t][1] = s_pts[idx * 3 + 1] - qy;
        nb[t][2] = s_pts[idx * 3 + 2] - qz;
        if (rowsum[idx] > 0.0f) atomicAdd(&vcnt[r], 1);
    }
    __syncthreads();
    if (t < 4) winv[t] = 1.0f / (float)max(vcnt[t], 1);
    __syncthreads();

    for (int tt = t; tt < 4 * HN * KTOT; tt += 256) {
        int r = tt / (HN * KTOT);
        int rem = tt % (HN * KTOT);
        int h = rem / KTOT, k = rem % KTOT;
        float dx = nb[r * HN + h][0] - kpts[k][0];
        float dy = nb[r * HN + h][1] - kpts[k][1];
        float dz = nb[r * HN + h][2] - kpts[k][2];
        float sq = dx * dx + dy * dy + dz * dz;
        float dist = sqrtf(fmaxf(sq, 1e-12f));
        float w = fmaxf(1.0f - dist * (1.0f / 0.6f), 0.0f);
        wts[r][h][k] = w * winv[r];
    }
    __syncthreads();

    {
        const int g = t >> 7;
        const int c = t & 127;
        for (int rr = 0; rr < 2; ++rr) {
            const int r = g + rr * 2;
            float acc[KTOT];
            #pragma unroll
            for (int k = 0; k < KTOT; ++k) acc[k] = 0.0f;
            for (int h = 0; h < HN; ++h) {
                int idx = nidx[r * HN + h];
                float xv = x[(size_t)idx * CH + c];
                const float4* wp = (const float4*)&wts[r][h][0];
                float4 wa = wp[0], wb = wp[1], wc = wp[2], wd = wp[3], we = wp[4];
                acc[0]  += wa.x * xv; acc[1]  += wa.y * xv; acc[2]  += wa.z * xv; acc[3]  += wa.w * xv;
                acc[4]  += wb.x * xv; acc[5]  += wb.y * xv; acc[6]  += wb.z * xv; acc[7]  += wb.w * xv;
                acc[8]  += wc.x * xv; acc[9]  += wc.y * xv; acc[10] += wc.z * xv; acc[11] += wc.w * xv;
                acc[12] += wd.x * xv; acc[13] += wd.y * xv; acc[14] += wd.z * xv; acc[15] += wd.w * xv;
                acc[16] += we.x * xv; acc[17] += we.y * xv; acc[18] += we.z * xv; acc[19] += we.w * xv;
            }
            #pragma unroll
            for (int k = 0; k < KTOT; ++k) wt[k][c][r] = acc[k];
        }
    }
    __syncthreads();

    {
        const int d = t & 127;
        const int half = t >> 7;
        const int c0 = half * 64;
        float o0 = 0.f, o1 = 0.f, o2 = 0.f, o3 = 0.f;
        if (d < DH) {
            for (int k = 0; k < KMINI; ++k) {
                const float* wp = &w_mini[((size_t)k * CH + c0) * DH + d];
                for (int c = c0; c < c0 + 64; ++c) {
                    float wv = *wp; wp += DH;
                    const float4 wtv = *(const float4*)&wt[k][c][0];
                    o0 += wv * wtv.x; o1 += wv * wtv.y; o2 += wv * wtv.z; o3 += wv * wtv.w;
                }
            }
        } else {
            const int dd = d - DH;
            for (int k = KMINI; k < KTOT; ++k) {
                const float* wp = &w_mid[((size_t)(k - KMINI) * CH + c0) * DH + dd];
                for (int c = c0; c < c0 + 64; ++c) {
                    float wv = *wp; wp += DH;
                    const float4 wtv = *(const float4*)&wt[k][c][0];
                    o0 += wv * wtv.x; o1 += wv * wtv.y; o2 += wv * wtv.z; o3 += wv * wtv.w;
                }
            }
        }
        if (half == 1) { part[d][0] = o0; part[d][1] = o1; part[d][2] = o2; part[d][3] = o3; }
        __syncthreads();
        if (half == 0) {
            o0 += part[d][0]; o1 += part[d][1]; o2 += part[d][2]; o3 += part[d][3];
            if (d < DH) {
                y1[(size_t)(n0 + 0) * DH + d] = o0;
                y1[(size_t)(n0 + 1) * DH + d] = o1;
                y1[(size_t)(n0 + 2) * DH + d] = o2;
                y1[(size_t)(n0 + 3) * DH + d] = o3;
            } else {
                const int dd = d - DH;
                y2[(size_t)(n0 + 0) * DH + dd] = o0;
                y2[(size_t)(n0 + 1) * DH + dd] = o1;
                y2[(size_t)(n0 + 2) * DH + dd] = o2;
                y2[(size_t)(n0 + 3) * DH + dd] = o3;
            }
        }
    }
}

__global__ __launch_bounds__(256) void k_segpart(
    const float* __restrict__ y1, const float* __restrict__ y2,
    const int* __restrict__ stacklen, float* __restrict__ segsum)
{
    const int t = threadIdx.x;
    const int ch = t & 63, grp = t >> 6;
    const int len0 = stacklen[0];
    float a0 = 0.f, a1 = 0.f, a2 = 0.f, a3 = 0.f;
    float b0 = 0.f, b1 = 0.f, b2 = 0.f, b3 = 0.f;
    for (int r = blockIdx.x * 4 + grp; r < NQ; r += 256 * 4) {
        float v1 = y1[(size_t)r * DH + ch];
        float v2 = y2[(size_t)r * DH + ch];
        bool in1 = (r >= len0);
        float m0 = in1 ? 0.f : 1.f, m1 = 1.f - m0;
        a0 += m0 * v1; a1 += m0 * v1 * v1; a2 += m1 * v1; a3 += m1 * v1 * v1;
        b0 += m0 * v2; b1 += m0 * v2 * v2; b2 += m1 * v2; b3 += m1 * v2 * v2;
    }
    __shared__ float red[4][8][64];
    red[grp][0][ch] = a0; red[grp][1][ch] = a1; red[grp][2][ch] = a2; red[grp][3][ch] = a3;
    red[grp][4][ch] = b0; red[grp][5][ch] = b1; red[grp][6][ch] = b2; red[grp][7][ch] = b3;
    __syncthreads();
    for (int tt = t; tt < 512; tt += 256) {
        int j = tt >> 6, c = tt & 63;
        float s = red[0][j][c] + red[1][j][c] + red[2][j][c] + red[3][j][c];
        atomicAdd(&segsum[j * 64 + c], s);
    }
}

__global__ __launch_bounds__(256) void k_tail(
    const float* __restrict__ y1, const float* __restrict__ y2,
    const float* __restrict__ segsum, const int* __restrict__ stacklen,
    const float* __restrict__ w_midmini, const float* __restrict__ w_final,
    float* __restrict__ outpre, float* __restrict__ bnsum, float* __restrict__ bnsq)
{
    __shared__ __align__(16) float sstat[4][2][64];
    __shared__ __align__(16) float sbuf[8][64];
    __shared__ __align__(16) float xc[8][128];
    __shared__ float lsum[2][128], lsq[2][128];
    const int n0 = blockIdx.x * 8;
    const int t = threadIdx.x;
    const int len0 = stacklen[0];

    {
        int combo = t >> 6, ch = t & 63;
        float cnt = (float)max((combo & 1) ? (NQ - len0) : len0, 1);
        float S = segsum[(combo * 2 + 0) * 64 + ch];
        float Q = segsum[(combo * 2 + 1) * 64 + ch];
        float mean = S / cnt;
        float var = Q / cnt - mean * mean;
        sstat[combo][0][ch] = mean;
        sstat[combo][1][ch] = rsqrtf(fmaxf(var, 0.f) + EPSN);
    }
    __syncthreads();

    for (int tt = t; tt < 8 * 64; tt += 256) {
        int r = tt >> 6, d = tt & 63;
        int n = n0 + r;
        int s = (n >= len0) ? 1 : 0;
        float x1n = (y1[(size_t)n * DH + d] - sstat[s][0][d]) * sstat[s][1][d];
        float x2n = (y2[(size_t)n * DH + d] - sstat[2 + s][0][d]) * sstat[2 + s][1][d];
        xc[r][d] = x1n;
        sbuf[r][d] = x1n + x2n;
    }
    __syncthreads();

    for (int tt = t; tt < 8 * 64; tt += 256) {
        int r = tt >> 6, d = tt & 63;
        float a = 0.f;
        const float4* wmr = (const float4*)&w_midmini[(size_t)d * 64];
        const float4* sv = (const float4*)&sbuf[r][0];
        #pragma unroll
        for (int e4 = 0; e4 < 16; ++e4) {
            float4 w4 = wmr[e4], s4 = sv[e4];
            a += w4.x * s4.x + w4.y * s4.y + w4.z * s4.z + w4.w * s4.w;
        }
        xc[r][64 + d] = a;
    }
    __syncthreads();

    {
        const int j = t & 127;
        const int g = t >> 7;
        float o0 = 0.f, o1 = 0.f, o2 = 0.f, o3 = 0.f;
        const float4* wfr = (const float4*)&w_final[(size_t)j * 128];
        #pragma unroll 8
        for (int i4 = 0; i4 < 32; ++i4) {
            float4 wf = wfr[i4];
            float4 a0 = *(const float4*)&xc[g + 0][i4 * 4];
            float4 a1 = *(const float4*)&xc[g + 2][i4 * 4];
            float4 a2 = *(const float4*)&xc[g + 4][i4 * 4];
            float4 a3 = *(const float4*)&xc[g + 6][i4 * 4];
            o0 += wf.x * a0.x + wf.y * a0.y + wf.z * a0.z + wf.w * a0.w;
            o1 += wf.x * a1.x + wf.y * a1.y + wf.z * a1.z + wf.w * a1.w;
            o2 += wf.x * a2.x + wf.y * a2.y + wf.z * a2.z + wf.w * a2.w;
            o3 += wf.x * a3.x + wf.y * a3.y + wf.z * a3.z + wf.w * a3.w;
        }
        outpre[(size_t)(n0 + g + 0) * CH + j] = o0;
        outpre[(size_t)(n0 + g + 2) * CH + j] = o1;
        outpre[(size_t)(n0 + g + 4) * CH + j] = o2;
        outpre[(size_t)(n0 + g + 6) * CH + j] = o3;
        lsum[g][j] = o0 + o1 + o2 + o3;
        lsq[g][j]  = o0 * o0 + o1 * o1 + o2 * o2 + o3 * o3;
        __syncthreads();
        if (g == 0) {
            atomicAdd(&bnsum[j], lsum[0][j] + lsum[1][j]);
            atomicAdd(&bnsq[j],  lsq[0][j] + lsq[1][j]);
        }
    }
}

// ---------------- kernel 5: BN apply + relu ----------------------------------
__global__ __launch_bounds__(256) void k_bnapply(const float* __restrict__ outpre,
    const float* __restrict__ bnsum, const float* __restrict__ bnsq,
    const float* __restrict__ gamma, const float* __restrict__ beta,
    float* __restrict__ out)
{
    int e4 = blockIdx.x * 256 + threadIdx.x;
    if (e4 >= NQ * CH / 4) return;
    int j0 = (e4 * 4) & 127;
    float4 v = ((const float4*)outpre)[e4];
    float vv[4] = {v.x, v.y, v.z, v.w};
    float res[4];
    #pragma unroll
    for (int i = 0; i < 4; ++i) {
        int j = j0 + i;
        float mean = bnsum[j] * (1.0f / NQ);
        float var = bnsq[j] * (1.0f / NQ) - mean * mean;
        float rstd = rsqrtf(fmaxf(var, 0.f) + EPSN);
        float r = (vv[i] - mean) * rstd * gamma[j] + beta[j];
        res[i] = fmaxf(r, 0.f);
    }
    ((float4*)out)[e4] = make_float4(res[0], res[1], res[2], res[3]);
}

extern "C" void kernel_launch(void* const* d_in, const int* in_sizes, int n_in,
                              void* d_out, int out_size, void* d_ws, size_t ws_size,
                              hipStream_t stream) {
    const float* q_pts     = (const float*)d_in[0];
    const float* s_pts     = (const float*)d_in[1];
    const int*   inds      = (const int*)d_in[2];
    const float* x         = (const float*)d_in[3];
    const int*   stacklen  = (const int*)d_in[4];
    const float* kp_mini   = (const float*)d_in[5];
    const float* w_mini    = (const float*)d_in[6];
    const float* kp_mid    = (const float*)d_in[7];
    const float* w_mid     = (const float*)d_in[8];
    const float* w_midmini = (const float*)d_in[9];
    const float* w_final   = (const float*)d_in[10];
    const float* gamma     = (const float*)d_in[11];
    const float* beta      = (const float*)d_in[12];

    float* ws      = (float*)d_ws;
    float* rowsum  = ws + OFF_ROWSUM;
    float* y1      = ws + OFF_Y1;
    float* y2      = ws + OFF_Y2;
    float* segsum  = ws + OFF_SEGSUM;
    float* bnsum   = ws + OFF_BNSUM;
    float* bnsq    = ws + OFF_BNSQ;
    float* outpre  = ws + OFF_OUTPRE;
    unsigned short* wswz  = (unsigned short*)(ws + OFF_WSWZ);
    unsigned short* cfrag = (unsigned short*)(ws + OFF_CFRAG);

    hipMemsetAsync(segsum, 0, 768 * sizeof(float), stream);

    if (ws_size >= (size_t)TOT_FLOATS * sizeof(float)) {
        k_prep<<<5000 + 1280 + 32, 256, 0, stream>>>(x, rowsum, w_mini, w_mid,
                                                     w_midmini, w_final, wswz, cfrag);
        k_fused2<<<NQ / 16, 256, 0, stream>>>(q_pts, s_pts, inds, x, kp_mini, kp_mid,
                                              rowsum, wswz, stacklen, y1, y2, segsum);
        k_tailmm<<<(NQ + 31) / 32, 128, 0, stream>>>(y1, y2, segsum, stacklen, cfrag,
                                                     outpre, bnsum, bnsq);
    } else {
        k_prep<<<5000, 256, 0, stream>>>(x, rowsum, w_mini, w_mid,
                                         w_midmini, w_final, wswz, cfrag);
        k_kpconv<<<NQ / 4, 256, 0, stream>>>(q_pts, s_pts, inds, x, kp_mini, kp_mid,
                                             w_mini, w_mid, rowsum, y1, y2);
        k_segpart<<<256, 256, 0, stream>>>(y1, y2, stacklen, segsum);
        k_tail<<<NQ / 8, 256, 0, stream>>>(y1, y2, segsum, stacklen, w_midmini, w_final,
                                           outpre, bnsum, bnsq);
    }

    k_bnapply<<<(NQ * CH / 4 + 255) / 256, 256, 0, stream>>>(outpre, bnsum, bnsq,
                                                             gamma, beta, (float*)d_out);
}

// Round 12
// 230.843 us; speedup vs baseline: 1.2130x; 1.0076x over previous
//
#include <hip/hip_runtime.h>
#include <math.h>

#define NQ 20000
#define MS 20000
#define HN 32
#define CH 128
#define DH 64
#define KTOT 20
#define KMINI 7
#define EPSN 1e-5f
#define NKT 80
#define KT_Y1 28

// workspace layout (float units)
#define OFF_ROWSUM 0
#define OFF_Y1     20480
#define OFF_Y2     (OFF_Y1 + NQ*DH)
#define OFF_SEGSUM (OFF_Y2 + NQ*DH)           // 512, zeroed
#define OFF_BNSUM  (OFF_SEGSUM + 512)         // 128, zeroed
#define OFF_BNSQ   (OFF_BNSUM + 128)          // 128, zeroed
#define OFF_OUTPRE (OFF_BNSQ + 128)           // NQ*CH
#define OFF_WSWZ   (OFF_OUTPRE + NQ*CH)       // 327680 ushort
#define OFF_CFRAG  (OFF_WSWZ + 163840)        // 16384 ushort
#define OFF_XBF    (OFF_CFRAG + 8192)         // NQ*CH ushort
#define TOT_FLOATS (OFF_XBF + NQ*CH/2)

// Pt LDS pitches (elements)
#define PK 40                 // k-row stride
#define PQ 840                // query stride (21*40)

typedef __attribute__((ext_vector_type(8))) short bf16x8;
typedef __attribute__((ext_vector_type(4))) float f32x4;
typedef __attribute__((ext_vector_type(4))) unsigned short us4;
typedef __attribute__((ext_vector_type(8))) unsigned short us8;

static __device__ inline unsigned short f2bf(float f) {
    unsigned int u = __float_as_uint(f);
    unsigned int r = (u + 0x7fffu + ((u >> 16) & 1u)) >> 16;
    return (unsigned short)r;
}

// --- kernel P: rowsum+x_bf (<1250) | weight swizzle (<2530) | C frags (rest) --
__global__ __launch_bounds__(256) void k_prep(
    const float* __restrict__ x, float* __restrict__ rowsum,
    const float* __restrict__ w_mini, const float* __restrict__ w_mid,
    const float* __restrict__ w_midmini, const float* __restrict__ w_final,
    unsigned short* __restrict__ wswz, unsigned short* __restrict__ cfrag,
    unsigned short* __restrict__ x_bf)
{
    const int t = threadIdx.x;
    if (blockIdx.x < 1250) {
        int row = blockIdx.x * 16 + (t >> 4);
        int l16 = t & 15;
        const float4* xr = (const float4*)&x[(size_t)row * CH + l16 * 8];
        float4 a = xr[0], b = xr[1];
        if (x_bf) {
            us8 v;
            v[0] = f2bf(a.x); v[1] = f2bf(a.y); v[2] = f2bf(a.z); v[3] = f2bf(a.w);
            v[4] = f2bf(b.x); v[5] = f2bf(b.y); v[6] = f2bf(b.z); v[7] = f2bf(b.w);
            *(us8*)&x_bf[(size_t)row * CH + l16 * 8] = v;
        }
        double s = (double)a.x + a.y + a.z + a.w + b.x + b.y + b.z + b.w;
        #pragma unroll
        for (int off = 8; off > 0; off >>= 1) s += __shfl_down(s, off, 64);
        if (l16 == 0) rowsum[row] = (float)s;
    } else if (blockIdx.x < 2530) {
        int gid = (blockIdx.x - 1250) * 256 + t;
        if (gid >= NKT * 8 * 512) return;
        int j = gid & 7;
        int l = (gid >> 3) & 63;
        int ntkt = gid >> 9;
        int nt = ntkt & 7;
        int kt = ntkt >> 3;
        int kg = kt * 32 + ((l >> 4) << 3) + j;
        int d  = nt * 16 + (l & 15);
        int k = kg >> 7, c = kg & 127;
        float v = 0.0f;
        if (k < KMINI && d < DH)        v = w_mini[((size_t)k * CH + c) * DH + d];
        else if (k >= KMINI && d >= DH) v = w_mid[((size_t)(k - KMINI) * CH + c) * DH + (d - DH)];
        wswz[gid] = f2bf(v);
    } else {
        int b2 = blockIdx.x - 2530;
        int kt = b2 >> 3, nt = b2 & 7;
        for (int e = t; e < 512; e += 256) {
            int l = e >> 3, j = e & 7;
            int i = kt * 32 + ((l >> 4) << 3) + j;
            int jcol = nt * 16 + (l & 15);
            const float* wfr = &w_final[(size_t)jcol * 128 + 64];
            int ec = i & 63;
            float dsum = 0.f;
            #pragma unroll 8
            for (int dd = 0; dd < 64; ++dd)
                dsum += w_midmini[dd * 64 + ec] * wfr[dd];
            float cv = dsum + ((i < 64) ? w_final[(size_t)jcol * 128 + i] : 0.f);
            cfrag[(size_t)(kt * 8 + nt) * 512 + e] = f2bf(cv);
        }
    }
}

// --------- kernel F2: fused gather(bf16) + MFMA weighting + MFMA main GEMM ----
// 1250 blocks x 256 thr; block = 16 queries. P lives only in LDS (c-quartered).
__global__ __launch_bounds__(256) void k_fused2(
    const float* __restrict__ q_pts, const float* __restrict__ s_pts,
    const int* __restrict__ inds, const unsigned short* __restrict__ x_bf,
    const float* __restrict__ kp_mini, const float* __restrict__ kp_mid,
    const float* __restrict__ rowsum, const unsigned short* __restrict__ wswz,
    const int* __restrict__ stacklen,
    float* __restrict__ y1, float* __restrict__ y2, float* __restrict__ segsum)
{
    __shared__ __align__(16) char pool[36096];
    unsigned short* Pt = (unsigned short*)pool;
    unsigned short* xg = (unsigned short*)(pool + 26880);
    float* nbv = (float*)pool;
    __shared__ int nidx[512];
    __shared__ float kpts[KTOT][3];
    __shared__ int vcnt[16];
    __shared__ float winv[16];

    const int t = threadIdx.x;
    const int l = t & 63;
    const int w = t >> 6;
    const int c16 = l & 15;
    const int quad = l >> 4;
    const int n0 = blockIdx.x * 16;

    if (t < KTOT * 3) {
        int k = t / 3, j = t % 3;
        kpts[k][j] = (k < KMINI) ? kp_mini[k * 3 + j] : kp_mid[(k - KMINI) * 3 + j];
    }
    if (t < 16) vcnt[t] = 0;
    __syncthreads();

    // phase 0: neighbor vectors + validity counts
    for (int tt = t; tt < 512; tt += 256) {
        int r = tt >> 5, h = tt & 31;
        int n = n0 + r;
        int idx = inds[n * HN + h];
        nidx[tt] = idx;
        float qx = q_pts[n * 3 + 0], qy = q_pts[n * 3 + 1], qz = q_pts[n * 3 + 2];
        nbv[tt * 3 + 0] = s_pts[idx * 3 + 0] - qx;
        nbv[tt * 3 + 1] = s_pts[idx * 3 + 1] - qy;
        nbv[tt * 3 + 2] = s_pts[idx * 3 + 2] - qz;
        if (rowsum[idx] > 0.0f) atomicAdd(&vcnt[r], 1);
    }
    __syncthreads();
    if (t < 16) winv[t] = 1.0f / (float)max(vcnt[t], 1);
    __syncthreads();

    // phase 1: influence A-fragments in registers
    bf16x8 aw0[4], aw1[4];
    const float k0x = kpts[c16][0], k0y = kpts[c16][1], k0z = kpts[c16][2];
    const bool v1 = (c16 < 4);
    const float k1x = v1 ? kpts[16 + c16][0] : 0.f;
    const float k1y = v1 ? kpts[16 + c16][1] : 0.f;
    const float k1z = v1 ? kpts[16 + c16][2] : 0.f;
    #pragma unroll
    for (int s = 0; s < 4; ++s) {
        const int qi = w * 4 + s;
        const float wi = winv[qi];
        const float* nvb = nbv + (qi * 32 + quad * 8) * 3;
        #pragma unroll
        for (int j = 0; j < 8; ++j) {
            float bx = nvb[j * 3 + 0], by = nvb[j * 3 + 1], bz = nvb[j * 3 + 2];
            float dx = bx - k0x, dy = by - k0y, dz = bz - k0z;
            float d = sqrtf(fmaxf(dx * dx + dy * dy + dz * dz, 1e-12f));
            aw0[s][j] = (short)f2bf(fmaxf(1.0f - d * (1.0f / 0.6f), 0.0f) * wi);
            if (v1) {
                dx = bx - k1x; dy = by - k1y; dz = bz - k1z;
                d = sqrtf(fmaxf(dx * dx + dy * dy + dz * dz, 1e-12f));
                aw1[s][j] = (short)f2bf(fmaxf(1.0f - d * (1.0f / 0.6f), 0.0f) * wi);
            } else {
                aw1[s][j] = 0;
            }
        }
    }
    __syncthreads();   // nbv dead; Pt/xg live

    f32x4 accY1 = (f32x4){0.f, 0.f, 0.f, 0.f};
    f32x4 accY2 = (f32x4){0.f, 0.f, 0.f, 0.f};
    unsigned short* xgw = xg + w * (32 * 36);
    const f32x4 zero4 = (f32x4){0.f, 0.f, 0.f, 0.f};

    for (int ktc = 0; ktc < 4; ++ktc) {
        #pragma unroll
        for (int s = 0; s < 4; ++s) {
            const int qi = w * 4 + s;
            // gather this c-quarter (bf16, no conversion): 2 iters x 16B
            #pragma unroll
            for (int i = 0; i < 2; ++i) {
                int gid = i * 64 + l;          // 0..127
                int h = gid >> 2, c8 = gid & 3;
                int idx = nidx[qi * 32 + h];
                us8 v = *(const us8*)&x_bf[(size_t)idx * CH + ktc * 32 + c8 * 8];
                us4 va = (us4){(unsigned short)v[0], (unsigned short)v[1],
                               (unsigned short)v[2], (unsigned short)v[3]};
                us4 vb = (us4){(unsigned short)v[4], (unsigned short)v[5],
                               (unsigned short)v[6], (unsigned short)v[7]};
                *(us4*)&xgw[h * 36 + c8 * 8]     = va;
                *(us4*)&xgw[h * 36 + c8 * 8 + 4] = vb;
            }
            asm volatile("s_waitcnt lgkmcnt(0)" ::: "memory");
            #pragma unroll
            for (int cf = 0; cf < 2; ++cf) {
                bf16x8 bb;
                #pragma unroll
                for (int j = 0; j < 8; ++j)
                    bb[j] = (short)xgw[(quad * 8 + j) * 36 + cf * 16 + c16];
                f32x4 d0 = __builtin_amdgcn_mfma_f32_16x16x32_bf16(aw0[s], bb, zero4, 0, 0, 0);
                f32x4 d1 = __builtin_amdgcn_mfma_f32_16x16x32_bf16(aw1[s], bb, zero4, 0, 0, 0);
                unsigned short* pq = Pt + qi * PQ + cf * 16 + c16;
                #pragma unroll
                for (int reg = 0; reg < 4; ++reg)
                    pq[(quad * 4 + reg) * PK] = f2bf(d0[reg]);
                if (quad == 0) {
                    #pragma unroll
                    for (int reg = 0; reg < 4; ++reg)
                        pq[(16 + reg) * PK] = f2bf(d1[reg]);
                }
            }
        }
        __syncthreads();   // Pt complete for this c-quarter

        #pragma unroll
        for (int k = 0; k < KTOT; ++k) {
            int ktg = k * 4 + ktc;
            bf16x8 a = *(const bf16x8*)&Pt[c16 * PQ + k * PK + quad * 8];
            int nt = (k < KMINI) ? w : 4 + w;
            bf16x8 b = *(const bf16x8*)&wswz[((size_t)(ktg * 8 + nt) << 9) + l * 8];
            if (k < KMINI) accY1 = __builtin_amdgcn_mfma_f32_16x16x32_bf16(a, b, accY1, 0, 0, 0);
            else           accY2 = __builtin_amdgcn_mfma_f32_16x16x32_bf16(a, b, accY2, 0, 0, 0);
        }
        __syncthreads();
    }

    // epilogue: store y + fused segment stats
    const int len0 = stacklen[0];
    const bool all0 = (n0 + 15 < len0);
    const bool all1 = (n0 >= len0);
    const int ch = w * 16 + c16;
    #pragma unroll
    for (int half = 0; half < 2; ++half) {
        f32x4 acc = half ? accY2 : accY1;
        float* yb = half ? y2 : y1;
        const int sbase = half ? 256 : 0;
        float s0 = 0.f, q0 = 0.f, s1 = 0.f, q1 = 0.f;
        #pragma unroll
        for (int reg = 0; reg < 4; ++reg) {
            int row = n0 + quad * 4 + reg;
            float v = acc[reg];
            yb[(size_t)row * DH + ch] = v;
            if (row < len0) { s0 += v; q0 += v * v; }
            else            { s1 += v; q1 += v * v; }
        }
        s0 += __shfl_xor(s0, 16); s0 += __shfl_xor(s0, 32);
        q0 += __shfl_xor(q0, 16); q0 += __shfl_xor(q0, 32);
        s1 += __shfl_xor(s1, 16); s1 += __shfl_xor(s1, 32);
        q1 += __shfl_xor(q1, 16); q1 += __shfl_xor(q1, 32);
        if (quad == 0) {
            if (!all1) {
                atomicAdd(&segsum[sbase + 0 * 64 + ch], s0);
                atomicAdd(&segsum[sbase + 1 * 64 + ch], q0);
            }
            if (!all0) {
                atomicAdd(&segsum[sbase + 2 * 64 + ch], s1);
                atomicAdd(&segsum[sbase + 3 * 64 + ch], q1);
            }
        }
    }
}

// -------- kernel T: fused tail GEMM (norm folded into A) + BN partials --------
__global__ __launch_bounds__(128) void k_tailmm(
    const float* __restrict__ y1, const float* __restrict__ y2,
    const float* __restrict__ segsum, const int* __restrict__ stacklen,
    const unsigned short* __restrict__ cfrag,
    float* __restrict__ outpre, float* __restrict__ bnsum, float* __restrict__ bnsq)
{
    __shared__ __align__(16) unsigned short alds[32 * 136];
    __shared__ float sstat[4][2][64];
    const int t = threadIdx.x;
    const int mb = blockIdx.x * 32;
    const int len0 = stacklen[0];

    for (int tt = t; tt < 256; tt += 128) {
        int combo = tt >> 6, ch = tt & 63;
        float cnt = (float)max((combo & 1) ? (NQ - len0) : len0, 1);
        float S = segsum[(combo * 2 + 0) * 64 + ch];
        float Q = segsum[(combo * 2 + 1) * 64 + ch];
        float mean = S / cnt;
        float var = Q / cnt - mean * mean;
        sstat[combo][0][ch] = mean;
        sstat[combo][1][ch] = rsqrtf(fmaxf(var, 0.f) + EPSN);
    }
    __syncthreads();

    for (int tt = t; tt < 32 * 32; tt += 128) {
        int r = tt >> 5, c4 = tt & 31;
        int n = mb + r;
        us4 v4 = (us4){0, 0, 0, 0};
        if (n < NQ) {
            int s = (n >= len0) ? 1 : 0;
            int c = c4 * 4;
            if (c < 64) {
                float4 yv = *(const float4*)&y1[(size_t)n * DH + c];
                v4[0] = f2bf((yv.x - sstat[s][0][c + 0]) * sstat[s][1][c + 0]);
                v4[1] = f2bf((yv.y - sstat[s][0][c + 1]) * sstat[s][1][c + 1]);
                v4[2] = f2bf((yv.z - sstat[s][0][c + 2]) * sstat[s][1][c + 2]);
                v4[3] = f2bf((yv.w - sstat[s][0][c + 3]) * sstat[s][1][c + 3]);
            } else {
                int c2 = c - 64;
                float4 yv = *(const float4*)&y2[(size_t)n * DH + c2];
                v4[0] = f2bf((yv.x - sstat[2 + s][0][c2 + 0]) * sstat[2 + s][1][c2 + 0]);
                v4[1] = f2bf((yv.y - sstat[2 + s][0][c2 + 1]) * sstat[2 + s][1][c2 + 1]);
                v4[2] = f2bf((yv.z - sstat[2 + s][0][c2 + 2]) * sstat[2 + s][1][c2 + 2]);
                v4[3] = f2bf((yv.w - sstat[2 + s][0][c2 + 3]) * sstat[2 + s][1][c2 + 3]);
            }
        }
        *(us4*)(alds + r * 136 + c4 * 4) = v4;
    }
    __syncthreads();

    const int l = t & 63, w = t >> 6;
    f32x4 acc[8];
    #pragma unroll
    for (int q = 0; q < 8; ++q) acc[q] = (f32x4){0.f, 0.f, 0.f, 0.f};

    const unsigned short* ap = alds + (w * 16 + (l & 15)) * 136 + ((l >> 4) << 3);
    const unsigned short* bp = cfrag + l * 8;
    #pragma unroll
    for (int kt = 0; kt < 4; ++kt) {
        bf16x8 a = *(const bf16x8*)(ap + kt * 32);
        #pragma unroll
        for (int nt = 0; nt < 8; ++nt) {
            bf16x8 b = *(const bf16x8*)(bp + (size_t)((kt * 8 + nt) << 9));
            acc[nt] = __builtin_amdgcn_mfma_f32_16x16x32_bf16(a, b, acc[nt], 0, 0, 0);
        }
    }

    const int quad = l >> 4, c16 = l & 15;
    #pragma unroll
    for (int nt = 0; nt < 8; ++nt) {
        float s = 0.f, q = 0.f;
        #pragma unroll
        for (int reg = 0; reg < 4; ++reg) {
            int row = mb + w * 16 + quad * 4 + reg;
            float v = acc[nt][reg];
            if (row < NQ) outpre[(size_t)row * CH + nt * 16 + c16] = v;
            else v = 0.f;
            s += v; q += v * v;
        }
        s += __shfl_xor(s, 16); s += __shfl_xor(s, 32);
        q += __shfl_xor(q, 16); q += __shfl_xor(q, 32);
        if (quad == 0) {
            atomicAdd(&bnsum[nt * 16 + c16], s);
            atomicAdd(&bnsq[nt * 16 + c16], q);
        }
    }
}

// ---------------- FALLBACK kernels (ws too small) -----------------------------
__global__ __launch_bounds__(256) void k_kpconv(
    const float* __restrict__ q_pts, const float* __restrict__ s_pts,
    const int* __restrict__ inds, const float* __restrict__ x,
    const float* __restrict__ kp_mini, const float* __restrict__ kp_mid,
    const float* __restrict__ w_mini, const float* __restrict__ w_mid,
    const float* __restrict__ rowsum,
    float* __restrict__ y1, float* __restrict__ y2)
{
    __shared__ __align__(16) float kpts[KTOT][3];
    __shared__ __align__(16) float nb[128][3];
    __shared__ int   nidx[128];
    __shared__ int   vcnt[4];
    __shared__ float winv[4];
    __shared__ __align__(16) float wts[4][HN][KTOT];
    __shared__ __align__(16) float wt[KTOT][CH][4];
    __shared__ __align__(16) float part[128][4];

    const int t = threadIdx.x;
    const int n0 = blockIdx.x * 4;

    if (t < KTOT * 3) {
        int k = t / 3, j = t % 3;
        kpts[k][j] = (k < KMINI) ? kp_mini[k * 3 + j] : kp_mid[(k - KMINI) * 3 + j];
    }
    if (t < 4) vcnt[t] = 0;
    __syncthreads();

    if (t < 128) {
        int r = t >> 5, h = t & 31;
        int n = n0 + r;
        int idx = inds[n * HN + h];
        nidx[t] = idx;
        float qx = q_pts[n * 3 + 0], qy = q_pts[n * 3 + 1], qz = q_pts[n * 3 + 2];
        nb[t][0] = s_pts[idx * 3 + 0] - qx;
        nb[t][1] = s_pts[idx * 3 + 1] - qy;
        nb[t][2] = s_pts[idx * 3 + 2] - qz;
        if (rowsum[idx] > 0.0f) atomicAdd(&vcnt[r], 1);
    }
    __syncthreads();
    if (t < 4) winv[t] = 1.0f / (float)max(vcnt[t], 1);
    __syncthreads();

    for (int tt = t; tt < 4 * HN * KTOT; tt += 256) {
        int r = tt / (HN * KTOT);
        int rem = tt % (HN * KTOT);
        int h = rem / KTOT, k = rem % KTOT;
        float dx = nb[r * HN + h][0] - kpts[k][0];
        float dy = nb[r * HN + h][1] - kpts[k][1];
        float dz = nb[r * HN + h][2] - kpts[k][2];
        float sq = dx * dx + dy * dy + dz * dz;
        float dist = sqrtf(fmaxf(sq, 1e-12f));
        float w = fmaxf(1.0f - dist * (1.0f / 0.6f), 0.0f);
        wts[r][h][k] = w * winv[r];
    }
    __syncthreads();

    {
        const int g = t >> 7;
        const int c = t & 127;
        for (int rr = 0; rr < 2; ++rr) {
            const int r = g + rr * 2;
            float acc[KTOT];
            #pragma unroll
            for (int k = 0; k < KTOT; ++k) acc[k] = 0.0f;
            for (int h = 0; h < HN; ++h) {
                int idx = nidx[r * HN + h];
                float xv = x[(size_t)idx * CH + c];
                const float4* wp = (const float4*)&wts[r][h][0];
                float4 wa = wp[0], wb = wp[1], wc = wp[2], wd = wp[3], we = wp[4];
                acc[0]  += wa.x * xv; acc[1]  += wa.y * xv; acc[2]  += wa.z * xv; acc[3]  += wa.w * xv;
                acc[4]  += wb.x * xv; acc[5]  += wb.y * xv; acc[6]  += wb.z * xv; acc[7]  += wb.w * xv;
                acc[8]  += wc.x * xv; acc[9]  += wc.y * xv; acc[10] += wc.z * xv; acc[11] += wc.w * xv;
                acc[12] += wd.x * xv; acc[13] += wd.y * xv; acc[14] += wd.z * xv; acc[15] += wd.w * xv;
                acc[16] += we.x * xv; acc[17] += we.y * xv; acc[18] += we.z * xv; acc[19] += we.w * xv;
            }
            #pragma unroll
            for (int k = 0; k < KTOT; ++k) wt[k][c][r] = acc[k];
        }
    }
    __syncthreads();

    {
        const int d = t & 127;
        const int half = t >> 7;
        const int c0 = half * 64;
        float o0 = 0.f, o1 = 0.f, o2 = 0.f, o3 = 0.f;
        if (d < DH) {
            for (int k = 0; k < KMINI; ++k) {
                const float* wp = &w_mini[((size_t)k * CH + c0) * DH + d];
                for (int c = c0; c < c0 + 64; ++c) {
                    float wv = *wp; wp += DH;
                    const float4 wtv = *(const float4*)&wt[k][c][0];
                    o0 += wv * wtv.x; o1 += wv * wtv.y; o2 += wv * wtv.z; o3 += wv * wtv.w;
                }
            }
        } else {
            const int dd = d - DH;
            for (int k = KMINI; k < KTOT; ++k) {
                const float* wp = &w_mid[((size_t)(k - KMINI) * CH + c0) * DH + dd];
                for (int c = c0; c < c0 + 64; ++c) {
                    float wv = *wp; wp += DH;
                    const float4 wtv = *(const float4*)&wt[k][c][0];
                    o0 += wv * wtv.x; o1 += wv * wtv.y; o2 += wv * wtv.z; o3 += wv * wtv.w;
                }
            }
        }
        if (half == 1) { part[d][0] = o0; part[d][1] = o1; part[d][2] = o2; part[d][3] = o3; }
        __syncthreads();
        if (half == 0) {
            o0 += part[d][0]; o1 += part[d][1]; o2 += part[d][2]; o3 += part[d][3];
            if (d < DH) {
                y1[(size_t)(n0 + 0) * DH + d] = o0;
                y1[(size_t)(n0 + 1) * DH + d] = o1;
                y1[(size_t)(n0 + 2) * DH + d] = o2;
                y1[(size_t)(n0 + 3) * DH + d] = o3;
            } else {
                const int dd = d - DH;
                y2[(size_t)(n0 + 0) * DH + dd] = o0;
                y2[(size_t)(n0 + 1) * DH + dd] = o1;
                y2[(size_t)(n0 + 2) * DH + dd] = o2;
                y2[(size_t)(n0 + 3) * DH + dd] = o3;
            }
        }
    }
}

__global__ __launch_bounds__(256) void k_segpart(
    const float* __restrict__ y1, const float* __restrict__ y2,
    const int* __restrict__ stacklen, float* __restrict__ segsum)
{
    const int t = threadIdx.x;
    const int ch = t & 63, grp = t >> 6;
    const int len0 = stacklen[0];
    float a0 = 0.f, a1 = 0.f, a2 = 0.f, a3 = 0.f;
    float b0 = 0.f, b1 = 0.f, b2 = 0.f, b3 = 0.f;
    for (int r = blockIdx.x * 4 + grp; r < NQ; r += 256 * 4) {
        float v1 = y1[(size_t)r * DH + ch];
        float v2 = y2[(size_t)r * DH + ch];
        bool in1 = (r >= len0);
        float m0 = in1 ? 0.f : 1.f, m1 = 1.f - m0;
        a0 += m0 * v1; a1 += m0 * v1 * v1; a2 += m1 * v1; a3 += m1 * v1 * v1;
        b0 += m0 * v2; b1 += m0 * v2 * v2; b2 += m1 * v2; b3 += m1 * v2 * v2;
    }
    __shared__ float red[4][8][64];
    red[grp][0][ch] = a0; red[grp][1][ch] = a1; red[grp][2][ch] = a2; red[grp][3][ch] = a3;
    red[grp][4][ch] = b0; red[grp][5][ch] = b1; red[grp][6][ch] = b2; red[grp][7][ch] = b3;
    __syncthreads();
    for (int tt = t; tt < 512; tt += 256) {
        int j = tt >> 6, c = tt & 63;
        float s = red[0][j][c] + red[1][j][c] + red[2][j][c] + red[3][j][c];
        atomicAdd(&segsum[j * 64 + c], s);
    }
}

__global__ __launch_bounds__(256) void k_tail(
    const float* __restrict__ y1, const float* __restrict__ y2,
    const float* __restrict__ segsum, const int* __restrict__ stacklen,
    const float* __restrict__ w_midmini, const float* __restrict__ w_final,
    float* __restrict__ outpre, float* __restrict__ bnsum, float* __restrict__ bnsq)
{
    __shared__ __align__(16) float sstat[4][2][64];
    __shared__ __align__(16) float sbuf[8][64];
    __shared__ __align__(16) float xc[8][128];
    __shared__ float lsum[2][128], lsq[2][128];
    const int n0 = blockIdx.x * 8;
    const int t = threadIdx.x;
    const int len0 = stacklen[0];

    {
        int combo = t >> 6, ch = t & 63;
        float cnt = (float)max((combo & 1) ? (NQ - len0) : len0, 1);
        float S = segsum[(combo * 2 + 0) * 64 + ch];
        float Q = segsum[(combo * 2 + 1) * 64 + ch];
        float mean = S / cnt;
        float var = Q / cnt - mean * mean;
        sstat[combo][0][ch] = mean;
        sstat[combo][1][ch] = rsqrtf(fmaxf(var, 0.f) + EPSN);
    }
    __syncthreads();

    for (int tt = t; tt < 8 * 64; tt += 256) {
        int r = tt >> 6, d = tt & 63;
        int n = n0 + r;
        int s = (n >= len0) ? 1 : 0;
        float x1n = (y1[(size_t)n * DH + d] - sstat[s][0][d]) * sstat[s][1][d];
        float x2n = (y2[(size_t)n * DH + d] - sstat[2 + s][0][d]) * sstat[2 + s][1][d];
        xc[r][d] = x1n;
        sbuf[r][d] = x1n + x2n;
    }
    __syncthreads();

    for (int tt = t; tt < 8 * 64; tt += 256) {
        int r = tt >> 6, d = tt & 63;
        float a = 0.f;
        const float4* wmr = (const float4*)&w_midmini[(size_t)d * 64];
        const float4* sv = (const float4*)&sbuf[r][0];
        #pragma unroll
        for (int e4 = 0; e4 < 16; ++e4) {
            float4 w4 = wmr[e4], s4 = sv[e4];
            a += w4.x * s4.x + w4.y * s4.y + w4.z * s4.z + w4.w * s4.w;
        }
        xc[r][64 + d] = a;
    }
    __syncthreads();

    {
        const int j = t & 127;
        const int g = t >> 7;
        float o0 = 0.f, o1 = 0.f, o2 = 0.f, o3 = 0.f;
        const float4* wfr = (const float4*)&w_final[(size_t)j * 128];
        #pragma unroll 8
        for (int i4 = 0; i4 < 32; ++i4) {
            float4 wf = wfr[i4];
            float4 a0 = *(const float4*)&xc[g + 0][i4 * 4];
            float4 a1 = *(const float4*)&xc[g + 2][i4 * 4];
            float4 a2 = *(const float4*)&xc[g + 4][i4 * 4];
            float4 a3 = *(const float4*)&xc[g + 6][i4 * 4];
            o0 += wf.x * a0.x + wf.y * a0.y + wf.z * a0.z + wf.w * a0.w;
            o1 += wf.x * a1.x + wf.y * a1.y + wf.z * a1.z + wf.w * a1.w;
            o2 += wf.x * a2.x + wf.y * a2.y + wf.z * a2.z + wf.w * a2.w;
            o3 += wf.x * a3.x + wf.y * a3.y + wf.z * a3.z + wf.w * a3.w;
        }
        outpre[(size_t)(n0 + g + 0) * CH + j] = o0;
        outpre[(size_t)(n0 + g + 2) * CH + j] = o1;
        outpre[(size_t)(n0 + g + 4) * CH + j] = o2;
        outpre[(size_t)(n0 + g + 6) * CH + j] = o3;
        lsum[g][j] = o0 + o1 + o2 + o3;
        lsq[g][j]  = o0 * o0 + o1 * o1 + o2 * o2 + o3 * o3;
        __syncthreads();
        if (g == 0) {
            atomicAdd(&bnsum[j], lsum[0][j] + lsum[1][j]);
            atomicAdd(&bnsq[j],  lsq[0][j] + lsq[1][j]);
        }
    }
}

// ---------------- kernel 5: BN apply + relu ----------------------------------
__global__ __launch_bounds__(256) void k_bnapply(const float* __restrict__ outpre,
    const float* __restrict__ bnsum, const float* __restrict__ bnsq,
    const float* __restrict__ gamma, const float* __restrict__ beta,
    float* __restrict__ out)
{
    int e4 = blockIdx.x * 256 + threadIdx.x;
    if (e4 >= NQ * CH / 4) return;
    int j0 = (e4 * 4) & 127;
    float4 v = ((const float4*)outpre)[e4];
    float vv[4] = {v.x, v.y, v.z, v.w};
    float res[4];
    #pragma unroll
    for (int i = 0; i < 4; ++i) {
        int j = j0 + i;
        float mean = bnsum[j] * (1.0f / NQ);
        float var = bnsq[j] * (1.0f / NQ) - mean * mean;
        float rstd = rsqrtf(fmaxf(var, 0.f) + EPSN);
        float r = (vv[i] - mean) * rstd * gamma[j] + beta[j];
        res[i] = fmaxf(r, 0.f);
    }
    ((float4*)out)[e4] = make_float4(res[0], res[1], res[2], res[3]);
}

extern "C" void kernel_launch(void* const* d_in, const int* in_sizes, int n_in,
                              void* d_out, int out_size, void* d_ws, size_t ws_size,
                              hipStream_t stream) {
    const float* q_pts     = (const float*)d_in[0];
    const float* s_pts     = (const float*)d_in[1];
    const int*   inds      = (const int*)d_in[2];
    const float* x         = (const float*)d_in[3];
    const int*   stacklen  = (const int*)d_in[4];
    const float* kp_mini   = (const float*)d_in[5];
    const float* w_mini    = (const float*)d_in[6];
    const float* kp_mid    = (const float*)d_in[7];
    const float* w_mid     = (const float*)d_in[8];
    const float* w_midmini = (const float*)d_in[9];
    const float* w_final   = (const float*)d_in[10];
    const float* gamma     = (const float*)d_in[11];
    const float* beta      = (const float*)d_in[12];

    float* ws      = (float*)d_ws;
    float* rowsum  = ws + OFF_ROWSUM;
    float* y1      = ws + OFF_Y1;
    float* y2      = ws + OFF_Y2;
    float* segsum  = ws + OFF_SEGSUM;
    float* bnsum   = ws + OFF_BNSUM;
    float* bnsq    = ws + OFF_BNSQ;
    float* outpre  = ws + OFF_OUTPRE;
    unsigned short* wswz  = (unsigned short*)(ws + OFF_WSWZ);
    unsigned short* cfrag = (unsigned short*)(ws + OFF_CFRAG);
    unsigned short* x_bf  = (unsigned short*)(ws + OFF_XBF);

    hipMemsetAsync(segsum, 0, 768 * sizeof(float), stream);

    if (ws_size >= (size_t)TOT_FLOATS * sizeof(float)) {
        k_prep<<<1250 + 1280 + 32, 256, 0, stream>>>(x, rowsum, w_mini, w_mid,
                                                     w_midmini, w_final, wswz, cfrag, x_bf);
        k_fused2<<<NQ / 16, 256, 0, stream>>>(q_pts, s_pts, inds, x_bf, kp_mini, kp_mid,
                                              rowsum, wswz, stacklen, y1, y2, segsum);
        k_tailmm<<<(NQ + 31) / 32, 128, 0, stream>>>(y1, y2, segsum, stacklen, cfrag,
                                                     outpre, bnsum, bnsq);
    } else {
        k_prep<<<1250, 256, 0, stream>>>(x, rowsum, w_mini, w_mid,
                                         w_midmini, w_final, wswz, cfrag, (unsigned short*)0);
        k_kpconv<<<NQ / 4, 256, 0, stream>>>(q_pts, s_pts, inds, x, kp_mini, kp_mid,
                                             w_mini, w_mid, rowsum, y1, y2);
        k_segpart<<<256, 256, 0, stream>>>(y1, y2, stacklen, segsum);
        k_tail<<<NQ / 8, 256, 0, stream>>>(y1, y2, segsum, stacklen, w_midmini, w_final,
                                           outpre, bnsum, bnsq);
    }

    k_bnapply<<<(NQ * CH / 4 + 255) / 256, 256, 0, stream>>>(outpre, bnsum, bnsq,
                                                             gamma, beta, (float*)d_out);
}